// Round 6
// baseline (274.103 us; speedup 1.0000x reference)
//
#include <hip/hip_runtime.h>
#include <hip/hip_cooperative_groups.h>
#include <math.h>

namespace cg = cooperative_groups;

// Problem constants
#define B_N 2048
#define T_N 128
#define C_N 3
#define J_N 25
#define E_N 64
#define TC  (T_N*C_N)    // 384 rows per batch
#define TCJ (TC*J_N)     // 9600 floats per batch
#define NQ4 (TCJ/4)      // 2400 float4 per batch

// Workspace layout (float offsets).
#define D_OFF      0                      // D [2048*2048] f32 (raw-h distances)
#define H_OFF      (B_N*B_N)              // h [2048*25] (raw)
#define BLO_OFF    (H_OFF + B_N*J_N)      // per-block lo [2048]
#define BHI_OFF    (BLO_OFF + B_N)        // per-block hi [2048]
#define DEATHS_OFF (BHI_OFF + B_N)        // f32 deaths[2047] (+1 pad -> even)
#define BEST_OFF   (DEATHS_OFF + B_N)     // u64 best[2][2048] (even off -> 8B aligned)

typedef unsigned long long u64;
#define U64MAX 0xFFFFFFFFFFFFFFFFull

// One block per batch. Coalesced float4 grid-stride (stride 250 preserves
// j-residue mod 25), register accumulate, tiny LDS reduce. Per-block lo/hi.
__global__ void __launch_bounds__(256) k_reduce(const float* __restrict__ x,
                                                float* __restrict__ ws) {
    __shared__ float4 part[250];
    __shared__ float S[100];
    __shared__ float Mj[25];
    const int t = threadIdx.x, b = blockIdx.x;
    const float4* x4 = (const float4*)(x + (size_t)b * TCJ);
    if (t < 250) {
        float4 a; a.x = a.y = a.z = a.w = 0.f;
        for (int idx = t; idx < NQ4; idx += 250) {
            float4 v = x4[idx];
            a.x += v.x; a.y += v.y; a.z += v.z; a.w += v.w;
        }
        part[t] = a;
    }
    __syncthreads();
    if (t < 25) {
        float4 s = part[t];
        #pragma unroll
        for (int g = 1; g < 10; ++g) {
            float4 v = part[t + 25 * g];
            s.x += v.x; s.y += v.y; s.z += v.z; s.w += v.w;
        }
        S[4*t] = s.x; S[4*t+1] = s.y; S[4*t+2] = s.z; S[4*t+3] = s.w;
    }
    __syncthreads();
    if (t < 25) Mj[t] = (S[t] + S[t+25] + S[t+50] + S[t+75]) * (1.0f / 384.0f);
    __syncthreads();
    if (t < 25) {
        float mj = Mj[t], acc = 0.f;
        #pragma unroll
        for (int i = 0; i < J_N; ++i) { float d = Mj[i] - mj; acc += d * d; }
        float hv = sqrtf(acc);
        ws[H_OFF + b * J_N + t] = hv;
        S[t] = hv;
    }
    __syncthreads();
    if (t == 0) {
        float lo = S[0], hi = S[0];
        #pragma unroll
        for (int i = 1; i < J_N; ++i) { lo = fminf(lo, S[i]); hi = fmaxf(hi, S[i]); }
        ws[BLO_OFF + b] = lo;
        ws[BHI_OFF + b] = hi;
    }
}

// 16x16 tile of the 2048x2048 raw-h distance matrix per block.
// (Min-max normalization is one affine map per coordinate -> distances scale
//  uniformly by rinv; MST is scale-invariant; rinv applied in struct phase.)
__global__ void k_dist(float* ws) {
    __shared__ float A[16][26], Bsh[16][26];
    const int tx = threadIdx.x, ty = threadIdx.y;
    const int flat = ty * 16 + tx;
    const int rowA = blockIdx.x * 16, rowB = blockIdx.y * 16;
    const float* h = ws + H_OFF;
    for (int idx = flat; idx < 16 * J_N; idx += 256) {
        int r = idx / J_N, c = idx % J_N;
        A[r][c]   = h[(rowA + r) * J_N + c];
        Bsh[r][c] = h[(rowB + r) * J_N + c];
    }
    __syncthreads();
    float acc = 0.f;
    #pragma unroll
    for (int k = 0; k < J_N; ++k) {
        float d = A[ty][k] - Bsh[tx][k];
        acc += d * d;
    }
    float* D = ws + D_OFF;
    D[(size_t)(rowA + ty) * B_N + rowB + tx] = sqrtf(fmaxf(acc, 1e-12f));
}

// Cooperative: entire Boruvka MST + structure layer in ONE kernel.
// 256 blocks x 1024 threads. Each block keeps its own comp[2048] in LDS and
// redundantly performs the (deterministic) union each round -> scan reads comp
// from local LDS; only best[] (16 KB/round) crosses blocks. best is
// double-buffered on round parity so exactly ONE grid.sync() per round is
// needed. Only block 0 writes deaths; the per-round edge count is identical
// in every block, so 'base' is tracked locally. Loop breaks uniformly on
// convergence (no stub rounds). Struct phase fused at the tail.
__global__ void __launch_bounds__(1024) k_mst(float* __restrict__ ws,
                                              const float* __restrict__ centres,
                                              const float* __restrict__ sharp,
                                              float* __restrict__ out) {
    cg::grid_group grid = cg::this_grid();
    __shared__ __align__(16) unsigned comp[B_N];  // 8 KB
    __shared__ u64 cb[B_N];                       // 16 KB
    __shared__ unsigned par[B_N];                 // 8 KB
    __shared__ u64 sc[16];
    __shared__ unsigned cnt_s;
    const int t = threadIdx.x, blk = blockIdx.x;
    const int w = t >> 6, lane = t & 63;
    const float* D = ws + D_OFF;
    float* deaths = ws + DEATHS_OFF;
    u64* bestbuf[2] = { (u64*)(ws + BEST_OFF), (u64*)(ws + BEST_OFF) + B_N };

    comp[t] = (unsigned)t;
    comp[t + 1024] = (unsigned)(t + 1024);
    __syncthreads();

    unsigned base = 0;
    for (int r = 0; r < 11; ++r) {
        // ---- scan: 16 waves, 2 per row; rows blk*8 .. blk*8+7 ----
        u64* bbuf = bestbuf[r & 1];
        const int row = blk * 8 + (w >> 1);
        const int half = w & 1;
        const unsigned ci = comp[row];
        const float4* row4 = (const float4*)(D + (size_t)row * B_N);
        const uint4* comp4 = (const uint4*)comp;
        u64 bst = U64MAX;
        #pragma unroll
        for (int k = 0; k < 4; ++k) {
            const int q = half * 256 + k * 64 + lane;   // float4 index in row
            float4 w4 = row4[q];
            uint4  c4 = comp4[q];
            const unsigned j0 = (unsigned)(q * 4);
            float wv[4] = {w4.x, w4.y, w4.z, w4.w};
            unsigned cv[4] = {c4.x, c4.y, c4.z, c4.w};
            #pragma unroll
            for (int m = 0; m < 4; ++m) {
                if (cv[m] != ci) {
                    unsigned j = j0 + m;
                    unsigned a = min((unsigned)row, j), b2 = max((unsigned)row, j);
                    u64 key = ((u64)__float_as_uint(wv[m]) << 32) | (a << 11) | b2;
                    if (key < bst) bst = key;
                }
            }
        }
        #pragma unroll
        for (int off = 32; off; off >>= 1) {
            u64 o = __shfl_down(bst, off);
            if (o < bst) bst = o;
        }
        if (lane == 0) sc[w] = bst;
        __syncthreads();
        if (lane == 0 && half == 0) {
            u64 a = sc[w], b2 = sc[w | 1];
            bbuf[row] = (a < b2) ? a : b2;
        }
        grid.sync();   // best visible everywhere; also block-level barrier

        // ---- union (replicated in every block, all in LDS) ----
        if (t == 0) cnt_s = 0u;
        cb[t] = U64MAX; cb[t + 1024] = U64MAX;
        __syncthreads();
        #pragma unroll
        for (int i = t; i < B_N; i += 1024) {
            u64 bk = bbuf[i];
            if (bk != U64MAX) atomicMin(&cb[comp[i]], bk);
        }
        __syncthreads();
        #pragma unroll
        for (int c = t; c < B_N; c += 1024) {
            u64 k = cb[c];
            unsigned p = (unsigned)c;
            if (k != U64MAX) {
                unsigned a  = (unsigned)((k >> 11) & 0x7FFu);
                unsigned b2 = (unsigned)(k & 0x7FFu);
                unsigned ca = comp[a], cbv = comp[b2];
                unsigned c2 = (ca == (unsigned)c) ? cbv : ca;
                p = c2;
                if (!(cb[c2] == k && c2 < (unsigned)c)) {  // mutual pick dedup
                    unsigned li = atomicAdd(&cnt_s, 1u);
                    if (blk == 0) deaths[base + li] = __uint_as_float((unsigned)(k >> 32));
                }
            }
            par[c] = p;
        }
        __syncthreads();
        // break 2-cycles (distinct keys -> hook graph has only 2-cycles)
        #pragma unroll
        for (int c = t; c < B_N; c += 1024) {
            unsigned p = par[c];
            if (p != (unsigned)c && par[p] == (unsigned)c && (unsigned)c < p) par[c] = (unsigned)c;
        }
        __syncthreads();
        // pointer jumping
        for (int it = 0; it < 11; ++it) {
            unsigned n0 = par[par[t]];
            unsigned n1 = par[par[t + 1024]];
            __syncthreads();
            par[t] = n0;
            par[t + 1024] = n1;
            __syncthreads();
        }
        // relabel
        #pragma unroll
        for (int i = t; i < B_N; i += 1024) comp[i] = par[comp[i]];
        __syncthreads();           // protect comp before next round's scan
        base += cnt_s;             // identical in every block
        if (base >= B_N - 1) break;  // uniform: no stub rounds
    }
    grid.sync();   // deaths (block 0's writes) visible to struct blocks

    // ---- struct phase: blocks 0..63, one e each ----
    if (blk >= E_N) return;
    __shared__ float redlo[16], redhi[16], wsum[16];
    float lo = fminf(ws[BLO_OFF + t], ws[BLO_OFF + t + 1024]);
    float hi = fmaxf(ws[BHI_OFF + t], ws[BHI_OFF + t + 1024]);
    #pragma unroll
    for (int off = 32; off; off >>= 1) {
        lo = fminf(lo, __shfl_down(lo, off));
        hi = fmaxf(hi, __shfl_down(hi, off));
    }
    if (lane == 0) { redlo[w] = lo; redhi[w] = hi; }
    __syncthreads();
    lo = redlo[0]; hi = redhi[0];
    #pragma unroll
    for (int k = 1; k < 16; ++k) { lo = fminf(lo, redlo[k]); hi = fmaxf(hi, redhi[k]); }
    float rng = hi - lo;
    float rinv = (rng > 1e-8f) ? 1.0f / rng : 0.0f;

    const int e = blk;
    const float c0 = centres[e * 2], c1 = centres[e * 2 + 1];
    const float s0 = sharp[e * 2],   s1 = sharp[e * 2 + 1];
    const float s1sq = s1 * s1;
    float acc = 0.f;
    for (int p = t; p < B_N - 1; p += 1024) {
        float d = deaths[p] * rinv - c1;
        acc += expf(-s1sq * d * d);
    }
    #pragma unroll
    for (int off = 32; off; off >>= 1) acc += __shfl_down(acc, off);
    if (lane == 0) wsum[w] = acc;
    __syncthreads();
    if (t == 0) {
        float tot = 0.f;
        #pragma unroll
        for (int k = 0; k < 16; ++k) tot += wsum[k];
        out[e] = expf(-s0 * s0 * c0 * c0) * tot;
    }
}

extern "C" void kernel_launch(void* const* d_in, const int* in_sizes, int n_in,
                              void* d_out, int out_size, void* d_ws, size_t ws_size,
                              hipStream_t stream) {
    const float* x       = (const float*)d_in[0];
    const float* centres = (const float*)d_in[1];
    const float* sharp   = (const float*)d_in[2];
    float* out = (float*)d_out;
    float* ws  = (float*)d_ws;

    hipLaunchKernelGGL(k_reduce, dim3(B_N),      dim3(256),    0, stream, x, ws);
    hipLaunchKernelGGL(k_dist,   dim3(128, 128), dim3(16, 16), 0, stream, ws);

    void* args[] = { (void*)&ws, (void*)&centres, (void*)&sharp, (void*)&out };
    hipLaunchCooperativeKernel((void*)k_mst, dim3(256), dim3(1024), args, 0, stream);
}

// Round 7
// 191.579 us; speedup vs baseline: 1.4308x; 1.4308x over previous
//
#include <hip/hip_runtime.h>
#include <math.h>

// Problem constants
#define B_N 2048
#define T_N 128
#define C_N 3
#define J_N 25
#define E_N 64
#define TC  (T_N*C_N)    // 384 rows per batch
#define TCJ (TC*J_N)     // 9600 floats per batch
#define NQ4 (TCJ/4)      // 2400 float4 per batch

// Workspace layout (float offsets). Total ~16.3 MiB (< prior rounds' usage).
#define D_OFF      0                       // D [2048*2048] f32 (raw-h distances)
#define H_OFF      (B_N*B_N)               // h [2048*25]
#define BLO_OFF    (H_OFF + B_N*J_N)       // per-block lo [2048]
#define BHI_OFF    (BLO_OFF + B_N)         // per-block hi [2048]
#define DEATHS_OFF (BHI_OFF + B_N)         // f32 deaths[2047] (even offset)
#define BEST_OFF   (DEATHS_OFF + B_N)      // u64 best[2][2048] (even -> 8B aligned)
#define COMP_OFF   (BEST_OFF + 4*B_N)      // u32 comp[2][2048]
#define GC_OFF     (COMP_OFF + 2*B_N)      // u32 gcnt[2]

typedef unsigned long long u64;
#define U64MAX 0xFFFFFFFFFFFFFFFFull

// One block per batch. Coalesced float4 grid-stride (stride 250 preserves
// j-residue mod 25), register accumulate, tiny LDS reduce. Per-block lo/hi.
__global__ void __launch_bounds__(256) k_reduce(const float* __restrict__ x,
                                                float* __restrict__ ws) {
    __shared__ float4 part[250];
    __shared__ float S[100];
    __shared__ float Mj[25];
    const int t = threadIdx.x, b = blockIdx.x;
    const float4* x4 = (const float4*)(x + (size_t)b * TCJ);
    if (t < 250) {
        float4 a; a.x = a.y = a.z = a.w = 0.f;
        for (int idx = t; idx < NQ4; idx += 250) {
            float4 v = x4[idx];
            a.x += v.x; a.y += v.y; a.z += v.z; a.w += v.w;
        }
        part[t] = a;
    }
    __syncthreads();
    if (t < 25) {
        float4 s = part[t];
        #pragma unroll
        for (int g = 1; g < 10; ++g) {
            float4 v = part[t + 25 * g];
            s.x += v.x; s.y += v.y; s.z += v.z; s.w += v.w;
        }
        S[4*t] = s.x; S[4*t+1] = s.y; S[4*t+2] = s.z; S[4*t+3] = s.w;
    }
    __syncthreads();
    if (t < 25) Mj[t] = (S[t] + S[t+25] + S[t+50] + S[t+75]) * (1.0f / 384.0f);
    __syncthreads();
    if (t < 25) {
        float mj = Mj[t], acc = 0.f;
        #pragma unroll
        for (int i = 0; i < J_N; ++i) { float d = Mj[i] - mj; acc += d * d; }
        float hv = sqrtf(acc);
        ws[H_OFF + b * J_N + t] = hv;
        S[t] = hv;
    }
    __syncthreads();
    if (t == 0) {
        float lo = S[0], hi = S[0];
        #pragma unroll
        for (int i = 1; i < J_N; ++i) { lo = fminf(lo, S[i]); hi = fmaxf(hi, S[i]); }
        ws[BLO_OFF + b] = lo;
        ws[BHI_OFF + b] = hi;
    }
}

// 16x16 tile of the 2048x2048 raw-h distance matrix per block.
// (Min-max normalization is one affine map per coordinate -> distances scale
//  uniformly; MST scale-invariant; rinv applied in k_final's struct phase.)
__global__ void k_dist(float* ws) {
    __shared__ float A[16][26], Bsh[16][26];
    const int tx = threadIdx.x, ty = threadIdx.y;
    const int flat = ty * 16 + tx;
    const int rowA = blockIdx.x * 16, rowB = blockIdx.y * 16;
    const float* h = ws + H_OFF;
    for (int idx = flat; idx < 16 * J_N; idx += 256) {
        int r = idx / J_N, c = idx % J_N;
        A[r][c]   = h[(rowA + r) * J_N + c];
        Bsh[r][c] = h[(rowB + r) * J_N + c];
    }
    __syncthreads();
    float acc = 0.f;
    #pragma unroll
    for (int k = 0; k < J_N; ++k) {
        float d = A[ty][k] - Bsh[tx][k];
        acc += d * d;
    }
    float* D = ws + D_OFF;
    D[(size_t)(rowA + ty) * B_N + rowB + tx] = sqrtf(fmaxf(acc, 1e-12f));
}

// Wave-per-row min-edge scan with identity comp (round 0). Writes best[0][row].
// blk0 also seeds comp[0]=identity and gcnt[0]=gcnt[1]=0.
__global__ void __launch_bounds__(1024) k_scan0(float* __restrict__ ws) {
    const int t = threadIdx.x, w = t >> 6, lane = t & 63;
    const int row = blockIdx.x * 16 + w;
    const float4* row4 = (const float4*)(ws + D_OFF + (size_t)row * B_N);
    u64 best = U64MAX;
    #pragma unroll
    for (int k = 0; k < 8; ++k) {
        const int q = k * 64 + lane;
        float4 w4 = row4[q];
        const unsigned j0 = (unsigned)(q * 4);
        float wv[4] = {w4.x, w4.y, w4.z, w4.w};
        #pragma unroll
        for (int m = 0; m < 4; ++m) {
            unsigned j = j0 + m;
            if (j != (unsigned)row) {
                unsigned a = min((unsigned)row, j), b2 = max((unsigned)row, j);
                u64 key = ((u64)__float_as_uint(wv[m]) << 32) | (a << 11) | b2;
                if (key < best) best = key;
            }
        }
    }
    #pragma unroll
    for (int off = 32; off; off >>= 1) {
        u64 o = __shfl_down(best, off);
        if (o < best) best = o;
    }
    if (lane == 0) ((u64*)(ws + BEST_OFF))[row] = best;
    if (blockIdx.x == 0) {
        unsigned* gc = (unsigned*)(ws + COMP_OFF);
        gc[t] = (unsigned)t; gc[t + 1024] = (unsigned)(t + 1024);
        if (t == 0) { ((unsigned*)(ws + GC_OFF))[0] = 0u; ((unsigned*)(ws + GC_OFF))[1] = 0u; }
    }
}

// One Boruvka round: replicated-in-LDS union of best[par_in] (comp from global
// parity buffer), then scan with the fresh LDS comp -> best[par_in^1].
// blk0 persists deaths/comp/gcnt. Barrier-free walk-to-root (static forest
// after 2-cycle break; racy path-compression writes are root-or-ancestor,
// always valid). On convergence blk0 writes BOTH gcnt slots so all later
// dispatches stub regardless of parity.
__global__ void __launch_bounds__(1024) k_round(float* __restrict__ ws, int par_in) {
    unsigned* gcnt = (unsigned*)(ws + GC_OFF);
    const unsigned base = gcnt[par_in];
    if (base >= B_N - 1) return;   // converged: stub
    __shared__ __align__(16) unsigned comp[B_N];  // 8 KB
    __shared__ u64 cb[B_N];                       // 16 KB
    __shared__ unsigned par[B_N];                 // 8 KB
    __shared__ unsigned cnt_s;
    const int t = threadIdx.x, blk = blockIdx.x;
    const unsigned* gcomp_in = (const unsigned*)(ws + COMP_OFF) + par_in * B_N;
    unsigned* gcomp_out = (unsigned*)(ws + COMP_OFF) + (par_in ^ 1) * B_N;
    const u64* bin = (const u64*)(ws + BEST_OFF) + par_in * B_N;
    u64* bout = (u64*)(ws + BEST_OFF) + (par_in ^ 1) * B_N;
    float* deaths = ws + DEATHS_OFF;

    if (t == 0) cnt_s = 0u;
    comp[t] = gcomp_in[t]; comp[t + 1024] = gcomp_in[t + 1024];
    cb[t] = U64MAX; cb[t + 1024] = U64MAX;
    __syncthreads();
    // per-component min of node candidates
    #pragma unroll
    for (int i = t; i < B_N; i += 1024) {
        u64 bk = bin[i];
        if (bk != U64MAX) atomicMin(&cb[comp[i]], bk);
    }
    __syncthreads();
    // hook + mutual-pick dedup + edge append (blk0 only writes)
    #pragma unroll
    for (int c = t; c < B_N; c += 1024) {
        u64 k = cb[c];
        unsigned p = (unsigned)c;
        if (k != U64MAX) {
            unsigned a  = (unsigned)((k >> 11) & 0x7FFu);
            unsigned b2 = (unsigned)(k & 0x7FFu);
            unsigned ca = comp[a], cbv = comp[b2];
            unsigned c2 = (ca == (unsigned)c) ? cbv : ca;
            p = c2;
            if (!(cb[c2] == k && c2 < (unsigned)c)) {
                unsigned li = atomicAdd(&cnt_s, 1u);
                if (blk == 0) deaths[base + li] = __uint_as_float((unsigned)(k >> 32));
            }
        }
        par[c] = p;
    }
    __syncthreads();
    // break 2-cycles (distinct keys -> only 2-cycles exist)
    #pragma unroll
    for (int c = t; c < B_N; c += 1024) {
        unsigned p = par[c];
        if (p != (unsigned)c && par[p] == (unsigned)c && (unsigned)c < p) par[c] = (unsigned)c;
    }
    __syncthreads();
    // walk to root, barrier-free (forest is static now)
    #pragma unroll
    for (int c = t; c < B_N; c += 1024) {
        unsigned r = par[c];
        while (true) { unsigned pr = par[r]; if (pr == r) break; r = pr; }
        par[c] = r;
    }
    __syncthreads();
    #pragma unroll
    for (int i = t; i < B_N; i += 1024) comp[i] = par[comp[i]];
    __syncthreads();
    const unsigned newbase = base + cnt_s;
    const bool conv = (newbase >= B_N - 1);
    if (blk == 0) {
        gcomp_out[t] = comp[t]; gcomp_out[t + 1024] = comp[t + 1024];
        if (t == 0) { gcnt[par_in ^ 1] = newbase; if (conv) gcnt[par_in] = newbase; }
    }
    if (conv) return;          // uniform across blocks (cnt_s deterministic)

    // ---- scan with fresh comp (LDS): one wave per row ----
    const int w = t >> 6, lane = t & 63;
    const int row = blk * 16 + w;
    const unsigned ci = comp[row];
    const float4* row4 = (const float4*)(ws + D_OFF + (size_t)row * B_N);
    const uint4* comp4 = (const uint4*)comp;
    u64 best = U64MAX;
    #pragma unroll
    for (int k = 0; k < 8; ++k) {
        const int q = k * 64 + lane;
        float4 w4 = row4[q];
        uint4  c4 = comp4[q];
        const unsigned j0 = (unsigned)(q * 4);
        float wv[4] = {w4.x, w4.y, w4.z, w4.w};
        unsigned cv[4] = {c4.x, c4.y, c4.z, c4.w};
        #pragma unroll
        for (int m = 0; m < 4; ++m) {
            if (cv[m] != ci) {
                unsigned j = j0 + m;
                unsigned a = min((unsigned)row, j), b2 = max((unsigned)row, j);
                u64 key = ((u64)__float_as_uint(wv[m]) << 32) | (a << 11) | b2;
                if (key < best) best = key;
            }
        }
    }
    #pragma unroll
    for (int off = 32; off; off >>= 1) {
        u64 o = __shfl_down(best, off);
        if (o < best) best = o;
    }
    if (lane == 0) bout[row] = best;
}

// Final: if not converged, one more union (single block, same logic), then the
// fused structure layer: out[e] = exp(-s0^2 c0^2) * sum_p exp(-s1^2 (rinv*d_p - c1)^2)
__global__ void __launch_bounds__(1024) k_final(float* __restrict__ ws,
                                                const float* __restrict__ centres,
                                                const float* __restrict__ sharp,
                                                float* __restrict__ out) {
    __shared__ __align__(16) unsigned comp[B_N];
    __shared__ u64 cb[B_N];
    __shared__ unsigned par[B_N];
    __shared__ unsigned cnt_s;
    __shared__ float redlo[16], redhi[16];
    const int t = threadIdx.x;
    unsigned* gcnt = (unsigned*)(ws + GC_OFF);
    float* deaths = ws + DEATHS_OFF;
    const unsigned base = gcnt[0];
    if (base < B_N - 1) {
        const unsigned* gcomp_in = (const unsigned*)(ws + COMP_OFF);  // parity 0
        const u64* bin = (const u64*)(ws + BEST_OFF);                 // parity 0
        if (t == 0) cnt_s = 0u;
        comp[t] = gcomp_in[t]; comp[t + 1024] = gcomp_in[t + 1024];
        cb[t] = U64MAX; cb[t + 1024] = U64MAX;
        __syncthreads();
        #pragma unroll
        for (int i = t; i < B_N; i += 1024) {
            u64 bk = bin[i];
            if (bk != U64MAX) atomicMin(&cb[comp[i]], bk);
        }
        __syncthreads();
        #pragma unroll
        for (int c = t; c < B_N; c += 1024) {
            u64 k = cb[c];
            if (k != U64MAX) {
                unsigned a  = (unsigned)((k >> 11) & 0x7FFu);
                unsigned b2 = (unsigned)(k & 0x7FFu);
                unsigned ca = comp[a], cbv = comp[b2];
                unsigned c2 = (ca == (unsigned)c) ? cbv : ca;
                if (!(cb[c2] == k && c2 < (unsigned)c)) {
                    unsigned li = atomicAdd(&cnt_s, 1u);
                    deaths[base + li] = __uint_as_float((unsigned)(k >> 32));
                }
            }
        }
        __syncthreads();
    }
    // ---- struct phase ----
    const int w = t >> 6, lane = t & 63;
    float lo = INFINITY, hi = -INFINITY;
    #pragma unroll
    for (int i = t; i < B_N; i += 1024) {
        lo = fminf(lo, ws[BLO_OFF + i]);
        hi = fmaxf(hi, ws[BHI_OFF + i]);
    }
    #pragma unroll
    for (int off = 32; off; off >>= 1) {
        lo = fminf(lo, __shfl_down(lo, off));
        hi = fmaxf(hi, __shfl_down(hi, off));
    }
    if (lane == 0) { redlo[w] = lo; redhi[w] = hi; }
    __syncthreads();
    lo = redlo[0]; hi = redhi[0];
    #pragma unroll
    for (int k = 1; k < 16; ++k) { lo = fminf(lo, redlo[k]); hi = fmaxf(hi, redhi[k]); }
    float rng = hi - lo;
    float rinv = (rng > 1e-8f) ? 1.0f / rng : 0.0f;

    for (int e = w; e < E_N; e += 16) {   // each wave: 4 elements
        const float c0 = centres[e * 2], c1 = centres[e * 2 + 1];
        const float s0 = sharp[e * 2],   s1 = sharp[e * 2 + 1];
        const float s1sq = s1 * s1;
        float acc = 0.f;
        for (int p = lane; p < B_N - 1; p += 64) {
            float d = deaths[p] * rinv - c1;
            acc += expf(-s1sq * d * d);
        }
        #pragma unroll
        for (int off = 32; off; off >>= 1) acc += __shfl_down(acc, off);
        if (lane == 0) out[e] = expf(-s0 * s0 * c0 * c0) * acc;
    }
}

extern "C" void kernel_launch(void* const* d_in, const int* in_sizes, int n_in,
                              void* d_out, int out_size, void* d_ws, size_t ws_size,
                              hipStream_t stream) {
    const float* x       = (const float*)d_in[0];
    const float* centres = (const float*)d_in[1];
    const float* sharp   = (const float*)d_in[2];
    float* out = (float*)d_out;
    float* ws  = (float*)d_ws;

    hipLaunchKernelGGL(k_reduce, dim3(B_N),      dim3(256),    0, stream, x, ws);
    hipLaunchKernelGGL(k_dist,   dim3(128, 128), dim3(16, 16), 0, stream, ws);
    hipLaunchKernelGGL(k_scan0,  dim3(128),      dim3(1024),   0, stream, ws);
    for (int r = 0; r < 10; ++r)
        hipLaunchKernelGGL(k_round, dim3(128), dim3(1024), 0, stream, ws, r & 1);
    hipLaunchKernelGGL(k_final, dim3(1), dim3(1024), 0, stream, ws, centres, sharp, out);
}

// Round 8
// 187.296 us; speedup vs baseline: 1.4635x; 1.0229x over previous
//
#include <hip/hip_runtime.h>
#include <math.h>

// Problem constants
#define B_N 2048
#define T_N 128
#define C_N 3
#define J_N 25
#define E_N 64
#define TC  (T_N*C_N)    // 384 rows per batch
#define TCJ (TC*J_N)     // 9600 floats per batch
#define NQ4 (TCJ/4)      // 2400 float4 per batch

// Workspace layout (float offsets). ~16.3 MiB.
#define D_OFF      0                       // D [2048*2048] f32 (raw-h distances)
#define H_OFF      (B_N*B_N)               // h [2048*25]
#define BLO_OFF    (H_OFF + B_N*J_N)       // per-block lo [2048]
#define BHI_OFF    (BLO_OFF + B_N)         // per-block hi [2048]
#define DEATHS_OFF (BHI_OFF + B_N)         // f32 deaths[2047]
#define BEST_OFF   (DEATHS_OFF + B_N)      // u64 best[2][2048] (even -> 8B aligned)
#define COMP_OFF   (BEST_OFF + 4*B_N)      // u32 comp[2][2048]
#define GC_OFF     (COMP_OFF + 2*B_N)      // u32 gcnt[2]
#define DC_OFF     (GC_OFF + 2)            // u32 Dc[64*64] contracted min-dist (f32 bits)

typedef unsigned long long u64;
#define U64MAX 0xFFFFFFFFFFFFFFFFull
#define U32INF 0xFFFFFFFFu

// One block per batch. Coalesced float4 grid-stride (stride 250 preserves
// j-residue mod 25), register accumulate, tiny LDS reduce. Per-block lo/hi.
__global__ void __launch_bounds__(256) k_reduce(const float* __restrict__ x,
                                                float* __restrict__ ws) {
    __shared__ float4 part[250];
    __shared__ float S[100];
    __shared__ float Mj[25];
    const int t = threadIdx.x, b = blockIdx.x;
    const float4* x4 = (const float4*)(x + (size_t)b * TCJ);
    if (t < 250) {
        float4 a; a.x = a.y = a.z = a.w = 0.f;
        for (int idx = t; idx < NQ4; idx += 250) {
            float4 v = x4[idx];
            a.x += v.x; a.y += v.y; a.z += v.z; a.w += v.w;
        }
        part[t] = a;
    }
    __syncthreads();
    if (t < 25) {
        float4 s = part[t];
        #pragma unroll
        for (int g = 1; g < 10; ++g) {
            float4 v = part[t + 25 * g];
            s.x += v.x; s.y += v.y; s.z += v.z; s.w += v.w;
        }
        S[4*t] = s.x; S[4*t+1] = s.y; S[4*t+2] = s.z; S[4*t+3] = s.w;
    }
    __syncthreads();
    if (t < 25) Mj[t] = (S[t] + S[t+25] + S[t+50] + S[t+75]) * (1.0f / 384.0f);
    __syncthreads();
    if (t < 25) {
        float mj = Mj[t], acc = 0.f;
        #pragma unroll
        for (int i = 0; i < J_N; ++i) { float d = Mj[i] - mj; acc += d * d; }
        float hv = sqrtf(acc);
        ws[H_OFF + b * J_N + t] = hv;
        S[t] = hv;
    }
    __syncthreads();
    if (t == 0) {
        float lo = S[0], hi = S[0];
        #pragma unroll
        for (int i = 1; i < J_N; ++i) { lo = fminf(lo, S[i]); hi = fmaxf(hi, S[i]); }
        ws[BLO_OFF + b] = lo;
        ws[BHI_OFF + b] = hi;
    }
}

// 16x16 tile of the 2048x2048 raw-h distance matrix per block.
// (Min-max normalization is one affine map per coordinate -> uniform scale;
//  MST scale-invariant; rinv applied in the struct phase.)
__global__ void k_dist(float* ws) {
    __shared__ float A[16][26], Bsh[16][26];
    const int tx = threadIdx.x, ty = threadIdx.y;
    const int flat = ty * 16 + tx;
    const int rowA = blockIdx.x * 16, rowB = blockIdx.y * 16;
    const float* h = ws + H_OFF;
    for (int idx = flat; idx < 16 * J_N; idx += 256) {
        int r = idx / J_N, c = idx % J_N;
        A[r][c]   = h[(rowA + r) * J_N + c];
        Bsh[r][c] = h[(rowB + r) * J_N + c];
    }
    __syncthreads();
    float acc = 0.f;
    #pragma unroll
    for (int k = 0; k < J_N; ++k) {
        float d = A[ty][k] - Bsh[tx][k];
        acc += d * d;
    }
    float* D = ws + D_OFF;
    D[(size_t)(rowA + ty) * B_N + rowB + tx] = sqrtf(fmaxf(acc, 1e-12f));
}

// Wave-per-row min-edge scan with identity comp (round 0). Writes best[0][row].
// blk0 also seeds comp[0]=identity, gcnt=0, Dc=INF.
__global__ void __launch_bounds__(1024) k_scan0(float* __restrict__ ws) {
    const int t = threadIdx.x, w = t >> 6, lane = t & 63;
    const int row = blockIdx.x * 16 + w;
    const float4* row4 = (const float4*)(ws + D_OFF + (size_t)row * B_N);
    u64 best = U64MAX;
    #pragma unroll
    for (int k = 0; k < 8; ++k) {
        const int q = k * 64 + lane;
        float4 w4 = row4[q];
        const unsigned j0 = (unsigned)(q * 4);
        float wv[4] = {w4.x, w4.y, w4.z, w4.w};
        #pragma unroll
        for (int m = 0; m < 4; ++m) {
            unsigned j = j0 + m;
            if (j != (unsigned)row) {
                unsigned a = min((unsigned)row, j), b2 = max((unsigned)row, j);
                u64 key = ((u64)__float_as_uint(wv[m]) << 32) | (a << 11) | b2;
                if (key < best) best = key;
            }
        }
    }
    #pragma unroll
    for (int off = 32; off; off >>= 1) {
        u64 o = __shfl_down(best, off);
        if (o < best) best = o;
    }
    if (lane == 0) ((u64*)(ws + BEST_OFF))[row] = best;
    if (blockIdx.x == 0) {
        unsigned* gc = (unsigned*)(ws + COMP_OFF);
        gc[t] = (unsigned)t; gc[t + 1024] = (unsigned)(t + 1024);
        unsigned* dc = (unsigned*)(ws + DC_OFF);
        #pragma unroll
        for (int i = 0; i < 4; ++i) dc[i * 1024 + t] = U32INF;
        if (t == 0) { ((unsigned*)(ws + GC_OFF))[0] = 0u; ((unsigned*)(ws + GC_OFF))[1] = 0u; }
    }
}

// One Boruvka round: replicated-in-LDS union of best[par_in], then (if do_scan)
// scan with the fresh LDS comp -> best[par_in^1]. Scan uses reuse pruning:
// if a row's previous best edge is still outgoing, it remains the row min
// (candidate set only shrinks). blk0 persists deaths/comp/gcnt.
__global__ void __launch_bounds__(1024) k_round(float* __restrict__ ws, int par_in,
                                                int do_scan) {
    unsigned* gcnt = (unsigned*)(ws + GC_OFF);
    const unsigned base = gcnt[par_in];
    if (base >= B_N - 1) return;   // converged: stub
    __shared__ __align__(16) unsigned comp[B_N];  // 8 KB
    __shared__ u64 cb[B_N];                       // 16 KB
    __shared__ unsigned par[B_N];                 // 8 KB
    __shared__ unsigned cnt_s;
    const int t = threadIdx.x, blk = blockIdx.x;
    const unsigned* gcomp_in = (const unsigned*)(ws + COMP_OFF) + par_in * B_N;
    unsigned* gcomp_out = (unsigned*)(ws + COMP_OFF) + (par_in ^ 1) * B_N;
    const u64* bin = (const u64*)(ws + BEST_OFF) + par_in * B_N;
    u64* bout = (u64*)(ws + BEST_OFF) + (par_in ^ 1) * B_N;
    float* deaths = ws + DEATHS_OFF;

    if (t == 0) cnt_s = 0u;
    comp[t] = gcomp_in[t]; comp[t + 1024] = gcomp_in[t + 1024];
    cb[t] = U64MAX; cb[t + 1024] = U64MAX;
    __syncthreads();
    #pragma unroll
    for (int i = t; i < B_N; i += 1024) {
        u64 bk = bin[i];
        if (bk != U64MAX) atomicMin(&cb[comp[i]], bk);
    }
    __syncthreads();
    #pragma unroll
    for (int c = t; c < B_N; c += 1024) {
        u64 k = cb[c];
        unsigned p = (unsigned)c;
        if (k != U64MAX) {
            unsigned a  = (unsigned)((k >> 11) & 0x7FFu);
            unsigned b2 = (unsigned)(k & 0x7FFu);
            unsigned ca = comp[a], cbv = comp[b2];
            unsigned c2 = (ca == (unsigned)c) ? cbv : ca;
            p = c2;
            if (!(cb[c2] == k && c2 < (unsigned)c)) {
                unsigned li = atomicAdd(&cnt_s, 1u);
                if (blk == 0) deaths[base + li] = __uint_as_float((unsigned)(k >> 32));
            }
        }
        par[c] = p;
    }
    __syncthreads();
    #pragma unroll
    for (int c = t; c < B_N; c += 1024) {
        unsigned p = par[c];
        if (p != (unsigned)c && par[p] == (unsigned)c && (unsigned)c < p) par[c] = (unsigned)c;
    }
    __syncthreads();
    #pragma unroll
    for (int c = t; c < B_N; c += 1024) {
        unsigned r = par[c];
        while (true) { unsigned pr = par[r]; if (pr == r) break; r = pr; }
        par[c] = r;
    }
    __syncthreads();
    #pragma unroll
    for (int i = t; i < B_N; i += 1024) comp[i] = par[comp[i]];
    __syncthreads();
    const unsigned newbase = base + cnt_s;
    if (blk == 0) {
        gcomp_out[t] = comp[t]; gcomp_out[t + 1024] = comp[t + 1024];
        if (t == 0) { gcnt[par_in ^ 1] = newbase; if (newbase >= B_N - 1) gcnt[par_in] = newbase; }
    }
    if (!do_scan || newbase >= B_N - 1) return;

    // ---- scan (one wave per row) with reuse pruning ----
    const int w = t >> 6, lane = t & 63;
    const int row = blk * 16 + w;
    const unsigned ci = comp[row];
    u64 prev = bin[row];
    {
        unsigned pa = (unsigned)((prev >> 11) & 0x7FFu);
        unsigned pb = (unsigned)(prev & 0x7FFu);
        unsigned jo = (pa == (unsigned)row) ? pb : pa;
        if (comp[jo] != ci) {          // still outgoing -> still the min
            if (lane == 0) bout[row] = prev;
            return;                    // wave-uniform exit
        }
    }
    const float4* row4 = (const float4*)(ws + D_OFF + (size_t)row * B_N);
    const uint4* comp4 = (const uint4*)comp;
    u64 best = U64MAX;
    #pragma unroll
    for (int k = 0; k < 8; ++k) {
        const int q = k * 64 + lane;
        float4 w4 = row4[q];
        uint4  c4 = comp4[q];
        const unsigned j0 = (unsigned)(q * 4);
        float wv[4] = {w4.x, w4.y, w4.z, w4.w};
        unsigned cv[4] = {c4.x, c4.y, c4.z, c4.w};
        #pragma unroll
        for (int m = 0; m < 4; ++m) {
            if (cv[m] != ci) {
                unsigned j = j0 + m;
                unsigned a = min((unsigned)row, j), b2 = max((unsigned)row, j);
                u64 key = ((u64)__float_as_uint(wv[m]) << 32) | (a << 11) | b2;
                if (key < best) best = key;
            }
        }
    }
    #pragma unroll
    for (int off = 32; off; off >>= 1) {
        u64 o = __shfl_down(best, off);
        if (o < best) best = o;
    }
    if (lane == 0) bout[row] = best;
}

// Contract: ncomp <= 64 guaranteed (5 unions done). 64 blocks x 32 rows.
// Replicated deterministic rank map (prefix scan of root flags), per-block
// partial Dc in LDS, merged via distinct-address global atomicMin.
__global__ void __launch_bounds__(1024) k_contract(float* __restrict__ ws) {
    if (((const unsigned*)(ws + GC_OFF))[1] >= B_N - 1) return;  // converged
    __shared__ unsigned cflag[B_N];   // flags -> ranks
    __shared__ unsigned Dcs[64 * 64]; // 16 KB partial contracted matrix
    __shared__ unsigned csum[16];
    const int t = threadIdx.x, blk = blockIdx.x;
    const unsigned lane = t & 63, w = t >> 6;
    const unsigned* gcomp1 = (const unsigned*)(ws + COMP_OFF) + B_N;  // parity 1

    cflag[t] = 0u; cflag[t + 1024] = 0u;
    #pragma unroll
    for (int i = 0; i < 4; ++i) Dcs[i * 1024 + t] = U32INF;
    __syncthreads();
    unsigned cA = gcomp1[t], cB = gcomp1[t + 1024];
    cflag[cA] = 1u; cflag[cB] = 1u;
    __syncthreads();
    // rank = exclusive prefix over flags (deterministic across blocks)
    unsigned f0 = cflag[2 * t], f1 = cflag[2 * t + 1];
    unsigned s = f0 + f1, sc = s;
    #pragma unroll
    for (int off = 1; off < 64; off <<= 1) {
        unsigned v = __shfl_up(sc, off);
        if (lane >= (unsigned)off) sc += v;
    }
    if (lane == 63) csum[w] = sc;
    __syncthreads();
    if (t < 16) {
        unsigned v = csum[t], acc = v;
        #pragma unroll
        for (int off = 1; off < 16; off <<= 1) {
            unsigned u2 = __shfl_up(acc, off);
            if (t >= off) acc += u2;
        }
        csum[t] = acc - v;   // exclusive
    }
    __syncthreads();
    unsigned off0 = csum[w] + (sc - s);
    __syncthreads();
    if (f0) cflag[2 * t] = off0;
    if (f1) cflag[2 * t + 1] = off0 + f0;
    __syncthreads();

    // scan 32 rows (2 per wave), LDS atomicMin into Dcs[ri*64+rj]
    #pragma unroll
    for (int q2 = 0; q2 < 2; ++q2) {
        const int row = blk * 32 + (int)w * 2 + q2;
        const unsigned ci = gcomp1[row];
        const unsigned ri = cflag[ci];
        const float4* row4 = (const float4*)(ws + D_OFF + (size_t)row * B_N);
        const uint4* comp4 = (const uint4*)gcomp1;
        #pragma unroll
        for (int k = 0; k < 8; ++k) {
            const int q = k * 64 + (int)lane;
            float4 w4 = row4[q];
            uint4  c4 = comp4[q];
            float wv[4] = {w4.x, w4.y, w4.z, w4.w};
            unsigned cv[4] = {c4.x, c4.y, c4.z, c4.w};
            #pragma unroll
            for (int m = 0; m < 4; ++m) {
                if (cv[m] != ci) {
                    unsigned rj = cflag[cv[m]];
                    atomicMin(&Dcs[ri * 64 + rj], __float_as_uint(wv[m]));
                }
            }
        }
    }
    __syncthreads();
    unsigned* gDc = (unsigned*)(ws + DC_OFF);
    #pragma unroll
    for (int i = t; i < 4096; i += 1024) {
        unsigned v = Dcs[i];
        if (v != U32INF) atomicMin(&gDc[i], v);
    }
}

// Finish: in-LDS Boruvka on the 64x64 contracted matrix (<=6 unions, wave0
// does each union), then the fused structure layer.
__global__ void __launch_bounds__(1024) k_finishstruct(float* __restrict__ ws,
                                                       const float* __restrict__ centres,
                                                       const float* __restrict__ sharp,
                                                       float* __restrict__ out) {
    __shared__ unsigned Dcs[64 * 64];
    __shared__ u64 cbf[64];
    __shared__ unsigned parf[64], ccomp[64];
    __shared__ unsigned cnt_s, base_s;
    __shared__ float redlo[16], redhi[16];
    const int t = threadIdx.x;
    const unsigned lane = t & 63, w = t >> 6;
    float* deaths = ws + DEATHS_OFF;
    const unsigned base0 = ((const unsigned*)(ws + GC_OFF))[1];

    if (base0 < B_N - 1) {
        const unsigned* gDc = (const unsigned*)(ws + DC_OFF);
        #pragma unroll
        for (int i = 0; i < 4; ++i) Dcs[i * 1024 + t] = gDc[i * 1024 + t];
        if (t < 64) ccomp[t] = (unsigned)t;
        if (t == 0) base_s = base0;
        __syncthreads();
        for (int iter = 0; iter < 7; ++iter) {
            if (t < 64) cbf[t] = U64MAX;
            if (t == 0) cnt_s = 0u;
            __syncthreads();
            // scan: wave w handles rows w*4..w*4+3; lane = column
            #pragma unroll
            for (int q2 = 0; q2 < 4; ++q2) {
                const int r = (int)w * 4 + q2;
                const unsigned cc = ccomp[r];
                unsigned wv = Dcs[r * 64 + lane];
                u64 key = U64MAX;
                if (wv != U32INF && ccomp[lane] != cc) {
                    unsigned a = min((unsigned)r, lane), b2 = max((unsigned)r, lane);
                    key = ((u64)wv << 32) | (a << 6) | b2;
                }
                #pragma unroll
                for (int off = 32; off; off >>= 1) {
                    u64 o = __shfl_down(key, off);
                    if (o < key) key = o;
                }
                if (lane == 0 && key != U64MAX) atomicMin(&cbf[cc], key);
            }
            __syncthreads();
            if (w == 0) {   // union entirely within wave 0 (lane = comp label)
                u64 k = cbf[lane];
                unsigned p = lane;
                bool add = false; float dw = 0.f;
                if (k != U64MAX) {
                    unsigned a = (unsigned)((k >> 6) & 63u), b2 = (unsigned)(k & 63u);
                    unsigned ca = ccomp[a], cbv = ccomp[b2];
                    unsigned c2 = (ca == lane) ? cbv : ca;
                    p = c2;
                    if (!(cbf[c2] == k && c2 < lane)) {
                        add = true; dw = __uint_as_float((unsigned)(k >> 32));
                    }
                }
                parf[lane] = p;
                unsigned pp = parf[lane];
                if (pp != lane && parf[pp] == lane && lane < pp) parf[lane] = lane;
                unsigned r2 = parf[lane];
                while (parf[r2] != r2) r2 = parf[r2];
                parf[lane] = r2;
                if (add) {
                    unsigned li = atomicAdd(&cnt_s, 1u);
                    deaths[base_s + li] = dw;
                }
                ccomp[lane] = parf[ccomp[lane]];
            }
            __syncthreads();
            if (t == 0) base_s += cnt_s;
            __syncthreads();
            if (base_s >= B_N - 1) break;
        }
        __threadfence_block();
        __syncthreads();
    }

    // ---- struct phase ----
    float lo = INFINITY, hi = -INFINITY;
    #pragma unroll
    for (int i = t; i < B_N; i += 1024) {
        lo = fminf(lo, ws[BLO_OFF + i]);
        hi = fmaxf(hi, ws[BHI_OFF + i]);
    }
    #pragma unroll
    for (int off = 32; off; off >>= 1) {
        lo = fminf(lo, __shfl_down(lo, off));
        hi = fmaxf(hi, __shfl_down(hi, off));
    }
    if (lane == 0) { redlo[w] = lo; redhi[w] = hi; }
    __syncthreads();
    lo = redlo[0]; hi = redhi[0];
    #pragma unroll
    for (int k = 1; k < 16; ++k) { lo = fminf(lo, redlo[k]); hi = fmaxf(hi, redhi[k]); }
    float rng = hi - lo;
    float rinv = (rng > 1e-8f) ? 1.0f / rng : 0.0f;

    for (int e = (int)w; e < E_N; e += 16) {
        const float c0 = centres[e * 2], c1 = centres[e * 2 + 1];
        const float s0 = sharp[e * 2],   s1 = sharp[e * 2 + 1];
        const float s1sq = s1 * s1;
        float acc = 0.f;
        for (int p = (int)lane; p < B_N - 1; p += 64) {
            float d = deaths[p] * rinv - c1;
            acc += expf(-s1sq * d * d);
        }
        #pragma unroll
        for (int off = 32; off; off >>= 1) acc += __shfl_down(acc, off);
        if (lane == 0) out[e] = expf(-s0 * s0 * c0 * c0) * acc;
    }
}

extern "C" void kernel_launch(void* const* d_in, const int* in_sizes, int n_in,
                              void* d_out, int out_size, void* d_ws, size_t ws_size,
                              hipStream_t stream) {
    const float* x       = (const float*)d_in[0];
    const float* centres = (const float*)d_in[1];
    const float* sharp   = (const float*)d_in[2];
    float* out = (float*)d_out;
    float* ws  = (float*)d_ws;

    hipLaunchKernelGGL(k_reduce,   dim3(B_N),      dim3(256),    0, stream, x, ws);
    hipLaunchKernelGGL(k_dist,     dim3(128, 128), dim3(16, 16), 0, stream, ws);
    hipLaunchKernelGGL(k_scan0,    dim3(128),      dim3(1024),   0, stream, ws);
    hipLaunchKernelGGL(k_round,    dim3(128),      dim3(1024),   0, stream, ws, 0, 1);
    hipLaunchKernelGGL(k_round,    dim3(128),      dim3(1024),   0, stream, ws, 1, 1);
    hipLaunchKernelGGL(k_round,    dim3(128),      dim3(1024),   0, stream, ws, 0, 1);
    hipLaunchKernelGGL(k_round,    dim3(128),      dim3(1024),   0, stream, ws, 1, 1);
    hipLaunchKernelGGL(k_round,    dim3(128),      dim3(1024),   0, stream, ws, 0, 0);
    hipLaunchKernelGGL(k_contract, dim3(64),       dim3(1024),   0, stream, ws);
    hipLaunchKernelGGL(k_finishstruct, dim3(1),    dim3(1024),   0, stream, ws, centres, sharp, out);
}

// Round 9
// 186.764 us; speedup vs baseline: 1.4676x; 1.0028x over previous
//
#include <hip/hip_runtime.h>
#include <math.h>

// Problem constants
#define B_N 2048
#define T_N 128
#define C_N 3
#define J_N 25
#define E_N 64
#define TC  (T_N*C_N)    // 384 rows per batch
#define TCJ (TC*J_N)     // 9600 floats per batch
#define NQ4 (TCJ/4)      // 2400 float4 per batch
#define NC  128          // contracted size (ncomp <= 128 after 4 unions)

// Workspace layout (float offsets). ~17.1 MiB.
#define D_OFF      0                       // D [2048*2048] f32 (raw-h distances)
#define H_OFF      (B_N*B_N)               // h [2048*25]
#define BLO_OFF    (H_OFF + B_N*J_N)       // per-block lo [2048]
#define BHI_OFF    (BLO_OFF + B_N)         // per-block hi [2048]
#define DEATHS_OFF (BHI_OFF + B_N)         // f32 deaths[2047]
#define BEST_OFF   (DEATHS_OFF + B_N)      // u64 best[2][2048] (even -> 8B aligned)
#define COMP_OFF   (BEST_OFF + 4*B_N)      // u32 comp[2][2048]
#define GC_OFF     (COMP_OFF + 2*B_N)      // u32 gcnt[2]
#define DC_OFF     (GC_OFF + 2)            // u32 Dc[128*128] contracted min-dist (f32 bits)

typedef unsigned long long u64;
#define U64MAX 0xFFFFFFFFFFFFFFFFull
#define U32INF 0xFFFFFFFFu

// One block per batch. Coalesced float4 grid-stride (stride 250 preserves
// j-residue mod 25), register accumulate, tiny LDS reduce. Per-block lo/hi.
__global__ void __launch_bounds__(256) k_reduce(const float* __restrict__ x,
                                                float* __restrict__ ws) {
    __shared__ float4 part[250];
    __shared__ float S[100];
    __shared__ float Mj[25];
    const int t = threadIdx.x, b = blockIdx.x;
    const float4* x4 = (const float4*)(x + (size_t)b * TCJ);
    if (t < 250) {
        float4 a; a.x = a.y = a.z = a.w = 0.f;
        for (int idx = t; idx < NQ4; idx += 250) {
            float4 v = x4[idx];
            a.x += v.x; a.y += v.y; a.z += v.z; a.w += v.w;
        }
        part[t] = a;
    }
    __syncthreads();
    if (t < 25) {
        float4 s = part[t];
        #pragma unroll
        for (int g = 1; g < 10; ++g) {
            float4 v = part[t + 25 * g];
            s.x += v.x; s.y += v.y; s.z += v.z; s.w += v.w;
        }
        S[4*t] = s.x; S[4*t+1] = s.y; S[4*t+2] = s.z; S[4*t+3] = s.w;
    }
    __syncthreads();
    if (t < 25) Mj[t] = (S[t] + S[t+25] + S[t+50] + S[t+75]) * (1.0f / 384.0f);
    __syncthreads();
    if (t < 25) {
        float mj = Mj[t], acc = 0.f;
        #pragma unroll
        for (int i = 0; i < J_N; ++i) { float d = Mj[i] - mj; acc += d * d; }
        float hv = sqrtf(acc);
        ws[H_OFF + b * J_N + t] = hv;
        S[t] = hv;
    }
    __syncthreads();
    if (t == 0) {
        float lo = S[0], hi = S[0];
        #pragma unroll
        for (int i = 1; i < J_N; ++i) { lo = fminf(lo, S[i]); hi = fmaxf(hi, S[i]); }
        ws[BLO_OFF + b] = lo;
        ws[BHI_OFF + b] = hi;
    }
}

// 32x32 tile of the 2048x2048 raw-h distance matrix per block (256 threads,
// 4 rows per thread). Pad 27 -> conflict-free LDS.
__global__ void __launch_bounds__(256) k_dist(float* ws) {
    __shared__ float A[32][27], Bsh[32][27];
    const int t = threadIdx.x;
    const int rowA = blockIdx.x * 32, rowB = blockIdx.y * 32;
    const float* h = ws + H_OFF;
    for (int idx = t; idx < 32 * J_N; idx += 256) {
        int r = idx / J_N, c = idx % J_N;
        A[r][c]   = h[(rowA + r) * J_N + c];
        Bsh[r][c] = h[(rowB + r) * J_N + c];
    }
    __syncthreads();
    const int tx = t & 31, ty = t >> 5;   // col, row-group
    float* D = ws + D_OFF;
    #pragma unroll
    for (int rr = 0; rr < 4; ++rr) {
        const int r = ty + rr * 8;
        float acc = 0.f;
        #pragma unroll
        for (int k = 0; k < J_N; ++k) {
            float d = A[r][k] - Bsh[tx][k];
            acc += d * d;
        }
        D[(size_t)(rowA + r) * B_N + rowB + tx] = sqrtf(fmaxf(acc, 1e-12f));
    }
}

// Wave-per-row min-edge scan with identity comp (round 0). Writes best[0][row].
// blk0 seeds comp[0]=identity + gcnt; blocks 0..15 init Dc=INF.
__global__ void __launch_bounds__(1024) k_scan0(float* __restrict__ ws) {
    const int t = threadIdx.x, w = t >> 6, lane = t & 63;
    const int row = blockIdx.x * 16 + w;
    const float4* row4 = (const float4*)(ws + D_OFF + (size_t)row * B_N);
    u64 best = U64MAX;
    #pragma unroll
    for (int k = 0; k < 8; ++k) {
        const int q = k * 64 + lane;
        float4 w4 = row4[q];
        const unsigned j0 = (unsigned)(q * 4);
        float wv[4] = {w4.x, w4.y, w4.z, w4.w};
        #pragma unroll
        for (int m = 0; m < 4; ++m) {
            unsigned j = j0 + m;
            if (j != (unsigned)row) {
                unsigned a = min((unsigned)row, j), b2 = max((unsigned)row, j);
                u64 key = ((u64)__float_as_uint(wv[m]) << 32) | (a << 11) | b2;
                if (key < best) best = key;
            }
        }
    }
    #pragma unroll
    for (int off = 32; off; off >>= 1) {
        u64 o = __shfl_down(best, off);
        if (o < best) best = o;
    }
    if (lane == 0) ((u64*)(ws + BEST_OFF))[row] = best;
    if (blockIdx.x < 16) ((unsigned*)(ws + DC_OFF))[blockIdx.x * 1024 + t] = U32INF;
    if (blockIdx.x == 0) {
        unsigned* gc = (unsigned*)(ws + COMP_OFF);
        gc[t] = (unsigned)t; gc[t + 1024] = (unsigned)(t + 1024);
        if (t == 0) { ((unsigned*)(ws + GC_OFF))[0] = 0u; ((unsigned*)(ws + GC_OFF))[1] = 0u; }
    }
}

// One Boruvka round: replicated-in-LDS union of best[par_in], then scan with
// the fresh LDS comp -> best[par_in^1]. Reuse pruning: if a row's previous
// best edge is still outgoing, it remains the row min. blk0 persists state.
__global__ void __launch_bounds__(1024) k_round(float* __restrict__ ws, int par_in) {
    unsigned* gcnt = (unsigned*)(ws + GC_OFF);
    const unsigned base = gcnt[par_in];
    if (base >= B_N - 1) return;   // converged: stub
    __shared__ __align__(16) unsigned comp[B_N];  // 8 KB
    __shared__ u64 cb[B_N];                       // 16 KB
    __shared__ unsigned par[B_N];                 // 8 KB
    __shared__ unsigned cnt_s;
    const int t = threadIdx.x, blk = blockIdx.x;
    const unsigned* gcomp_in = (const unsigned*)(ws + COMP_OFF) + par_in * B_N;
    unsigned* gcomp_out = (unsigned*)(ws + COMP_OFF) + (par_in ^ 1) * B_N;
    const u64* bin = (const u64*)(ws + BEST_OFF) + par_in * B_N;
    u64* bout = (u64*)(ws + BEST_OFF) + (par_in ^ 1) * B_N;
    float* deaths = ws + DEATHS_OFF;

    if (t == 0) cnt_s = 0u;
    comp[t] = gcomp_in[t]; comp[t + 1024] = gcomp_in[t + 1024];
    cb[t] = U64MAX; cb[t + 1024] = U64MAX;
    __syncthreads();
    #pragma unroll
    for (int i = t; i < B_N; i += 1024) {
        u64 bk = bin[i];
        if (bk != U64MAX) atomicMin(&cb[comp[i]], bk);
    }
    __syncthreads();
    #pragma unroll
    for (int c = t; c < B_N; c += 1024) {
        u64 k = cb[c];
        unsigned p = (unsigned)c;
        if (k != U64MAX) {
            unsigned a  = (unsigned)((k >> 11) & 0x7FFu);
            unsigned b2 = (unsigned)(k & 0x7FFu);
            unsigned ca = comp[a], cbv = comp[b2];
            unsigned c2 = (ca == (unsigned)c) ? cbv : ca;
            p = c2;
            if (!(cb[c2] == k && c2 < (unsigned)c)) {
                unsigned li = atomicAdd(&cnt_s, 1u);
                if (blk == 0) deaths[base + li] = __uint_as_float((unsigned)(k >> 32));
            }
        }
        par[c] = p;
    }
    __syncthreads();
    #pragma unroll
    for (int c = t; c < B_N; c += 1024) {
        unsigned p = par[c];
        if (p != (unsigned)c && par[p] == (unsigned)c && (unsigned)c < p) par[c] = (unsigned)c;
    }
    __syncthreads();
    #pragma unroll
    for (int c = t; c < B_N; c += 1024) {
        unsigned r = par[c];
        while (true) { unsigned pr = par[r]; if (pr == r) break; r = pr; }
        par[c] = r;
    }
    __syncthreads();
    #pragma unroll
    for (int i = t; i < B_N; i += 1024) comp[i] = par[comp[i]];
    __syncthreads();
    const unsigned newbase = base + cnt_s;
    if (blk == 0) {
        gcomp_out[t] = comp[t]; gcomp_out[t + 1024] = comp[t + 1024];
        if (t == 0) { gcnt[par_in ^ 1] = newbase; if (newbase >= B_N - 1) gcnt[par_in] = newbase; }
    }
    if (newbase >= B_N - 1) return;

    // ---- scan (one wave per row) with reuse pruning ----
    const int w = t >> 6, lane = t & 63;
    const int row = blk * 16 + w;
    const unsigned ci = comp[row];
    u64 prev = bin[row];
    {
        unsigned pa = (unsigned)((prev >> 11) & 0x7FFu);
        unsigned pb = (unsigned)(prev & 0x7FFu);
        unsigned jo = (pa == (unsigned)row) ? pb : pa;
        if (comp[jo] != ci) {          // still outgoing -> still the min
            if (lane == 0) bout[row] = prev;
            return;                    // wave-uniform exit
        }
    }
    const float4* row4 = (const float4*)(ws + D_OFF + (size_t)row * B_N);
    const uint4* comp4 = (const uint4*)comp;
    u64 best = U64MAX;
    #pragma unroll
    for (int k = 0; k < 8; ++k) {
        const int q = k * 64 + lane;
        float4 w4 = row4[q];
        uint4  c4 = comp4[q];
        const unsigned j0 = (unsigned)(q * 4);
        float wv[4] = {w4.x, w4.y, w4.z, w4.w};
        unsigned cv[4] = {c4.x, c4.y, c4.z, c4.w};
        #pragma unroll
        for (int m = 0; m < 4; ++m) {
            if (cv[m] != ci) {
                unsigned j = j0 + m;
                unsigned a = min((unsigned)row, j), b2 = max((unsigned)row, j);
                u64 key = ((u64)__float_as_uint(wv[m]) << 32) | (a << 11) | b2;
                if (key < best) best = key;
            }
        }
    }
    #pragma unroll
    for (int off = 32; off; off >>= 1) {
        u64 o = __shfl_down(best, off);
        if (o < best) best = o;
    }
    if (lane == 0) bout[row] = best;
}

// 4th union (par_in=1) FUSED with contraction to a 128x128 matrix.
// After the replicated union, comp is in LDS in every block; build the
// deterministic rank map (prefix scan of root flags), scan this block's 16
// rows into a 64 KB LDS partial Dc, merge via distinct-address global
// atomicMin. LDS overlay: phase A uses ovl as cb+par, phase B as Dcs.
__global__ void __launch_bounds__(1024) k_round4c(float* __restrict__ ws) {
    unsigned* gcnt = (unsigned*)(ws + GC_OFF);
    const unsigned base = gcnt[1];
    if (base >= B_N - 1) return;   // converged: stub
    __shared__ __align__(16) unsigned comp[B_N];   // 8 KB
    __shared__ __align__(16) unsigned ovl[NC*NC];  // 64 KB overlay
    __shared__ unsigned cflag[B_N];                // 8 KB
    __shared__ unsigned cnt_s, csum[16];
    u64* cb = (u64*)ovl;              // 16 KB (ovl[0..4095])
    unsigned* par = ovl + 4096;       // 8 KB  (ovl[4096..6143])
    const int t = threadIdx.x, blk = blockIdx.x;
    const unsigned* gcomp_in = (const unsigned*)(ws + COMP_OFF) + B_N;  // parity 1
    const u64* bin = (const u64*)(ws + BEST_OFF) + B_N;                 // parity 1
    float* deaths = ws + DEATHS_OFF;

    // ---- phase A: union (identical logic to k_round) ----
    if (t == 0) cnt_s = 0u;
    comp[t] = gcomp_in[t]; comp[t + 1024] = gcomp_in[t + 1024];
    cb[t] = U64MAX; cb[t + 1024] = U64MAX;
    __syncthreads();
    #pragma unroll
    for (int i = t; i < B_N; i += 1024) {
        u64 bk = bin[i];
        if (bk != U64MAX) atomicMin(&cb[comp[i]], bk);
    }
    __syncthreads();
    #pragma unroll
    for (int c = t; c < B_N; c += 1024) {
        u64 k = cb[c];
        unsigned p = (unsigned)c;
        if (k != U64MAX) {
            unsigned a  = (unsigned)((k >> 11) & 0x7FFu);
            unsigned b2 = (unsigned)(k & 0x7FFu);
            unsigned ca = comp[a], cbv = comp[b2];
            unsigned c2 = (ca == (unsigned)c) ? cbv : ca;
            p = c2;
            if (!(cb[c2] == k && c2 < (unsigned)c)) {
                unsigned li = atomicAdd(&cnt_s, 1u);
                if (blk == 0) deaths[base + li] = __uint_as_float((unsigned)(k >> 32));
            }
        }
        par[c] = p;
    }
    __syncthreads();
    #pragma unroll
    for (int c = t; c < B_N; c += 1024) {
        unsigned p = par[c];
        if (p != (unsigned)c && par[p] == (unsigned)c && (unsigned)c < p) par[c] = (unsigned)c;
    }
    __syncthreads();
    #pragma unroll
    for (int c = t; c < B_N; c += 1024) {
        unsigned r = par[c];
        while (true) { unsigned pr = par[r]; if (pr == r) break; r = pr; }
        par[c] = r;
    }
    __syncthreads();
    #pragma unroll
    for (int i = t; i < B_N; i += 1024) comp[i] = par[comp[i]];
    __syncthreads();
    const unsigned newbase = base + cnt_s;
    if (blk == 0 && t == 0) { gcnt[0] = newbase; gcnt[1] = newbase; }
    if (newbase >= B_N - 1) return;   // MST complete: no contraction needed

    // ---- phase B: rank map (deterministic across blocks) ----
    cflag[t] = 0u; cflag[t + 1024] = 0u;
    __syncthreads();
    cflag[comp[t]] = 1u; cflag[comp[t + 1024]] = 1u;
    __syncthreads();
    const unsigned lane = t & 63, w = t >> 6;
    unsigned f0 = cflag[2 * t], f1 = cflag[2 * t + 1];
    unsigned s = f0 + f1, sc = s;
    #pragma unroll
    for (int off = 1; off < 64; off <<= 1) {
        unsigned v = __shfl_up(sc, off);
        if (lane >= (unsigned)off) sc += v;
    }
    if (lane == 63) csum[w] = sc;
    __syncthreads();
    if (t < 16) {
        unsigned v = csum[t], acc = v;
        #pragma unroll
        for (int off = 1; off < 16; off <<= 1) {
            unsigned u2 = __shfl_up(acc, off);
            if (t >= off) acc += u2;
        }
        csum[t] = acc - v;   // exclusive
    }
    __syncthreads();
    unsigned off0 = csum[w] + (sc - s);
    __syncthreads();
    if (f0) cflag[2 * t] = off0;
    if (f1) cflag[2 * t + 1] = off0 + f0;
    __syncthreads();

    // ---- phase C: contract this block's 16 rows into LDS Dcs = ovl ----
    #pragma unroll
    for (int i = 0; i < 16; ++i) ovl[i * 1024 + t] = U32INF;
    __syncthreads();
    {
        const int row = blk * 16 + (int)w;
        const unsigned ci = comp[row];
        const unsigned ri = cflag[ci];
        const float4* row4 = (const float4*)(ws + D_OFF + (size_t)row * B_N);
        const uint4* comp4 = (const uint4*)comp;
        #pragma unroll
        for (int k = 0; k < 8; ++k) {
            const int q = k * 64 + (int)lane;
            float4 w4 = row4[q];
            uint4  c4 = comp4[q];
            float wv[4] = {w4.x, w4.y, w4.z, w4.w};
            unsigned cv[4] = {c4.x, c4.y, c4.z, c4.w};
            #pragma unroll
            for (int m = 0; m < 4; ++m) {
                if (cv[m] != ci) atomicMin(&ovl[ri * NC + cflag[cv[m]]], __float_as_uint(wv[m]));
            }
        }
    }
    __syncthreads();
    unsigned* gDc = (unsigned*)(ws + DC_OFF);
    #pragma unroll
    for (int i = t; i < NC * NC; i += 1024) {
        unsigned v = ovl[i];
        if (v != U32INF) atomicMin(&gDc[i], v);
    }
}

// Finish: in-LDS Boruvka on the 128x128 contracted matrix (<=7 unions,
// t<128 does each union), then the fused structure layer.
__global__ void __launch_bounds__(1024) k_finishstruct(float* __restrict__ ws,
                                                       const float* __restrict__ centres,
                                                       const float* __restrict__ sharp,
                                                       float* __restrict__ out) {
    __shared__ unsigned Dcs[NC * NC];   // 64 KB
    __shared__ u64 cbf[NC];
    __shared__ unsigned parf[NC], ccomp[NC];
    __shared__ unsigned cnt_s, base_s;
    __shared__ float redlo[16], redhi[16];
    const int t = threadIdx.x;
    const int lane = t & 63, w = t >> 6;
    float* deaths = ws + DEATHS_OFF;
    const unsigned base0 = ((const unsigned*)(ws + GC_OFF))[0];

    if (base0 < B_N - 1) {
        const unsigned* gDc = (const unsigned*)(ws + DC_OFF);
        #pragma unroll
        for (int i = 0; i < 16; ++i) Dcs[i * 1024 + t] = gDc[i * 1024 + t];
        if (t < NC) ccomp[t] = (unsigned)t;
        if (t == 0) base_s = base0;
        __syncthreads();
        for (int iter = 0; iter < 7; ++iter) {
            if (t < NC) cbf[t] = U64MAX;
            if (t == 0) cnt_s = 0u;
            __syncthreads();
            // scan: wave w -> rows w*8..w*8+7; lane covers 2 cols
            #pragma unroll
            for (int q = 0; q < 8; ++q) {
                const int r = w * 8 + q;
                const unsigned cc = ccomp[r];
                u64 key = U64MAX;
                #pragma unroll
                for (int hh = 0; hh < 2; ++hh) {
                    const int c = lane + hh * 64;
                    unsigned wv = Dcs[r * NC + c];
                    if (wv != U32INF && ccomp[c] != cc) {
                        unsigned a = min((unsigned)r, (unsigned)c);
                        unsigned b2 = max((unsigned)r, (unsigned)c);
                        u64 k2 = ((u64)wv << 32) | (a << 7) | b2;
                        if (k2 < key) key = k2;
                    }
                }
                #pragma unroll
                for (int off = 32; off; off >>= 1) {
                    u64 o = __shfl_down(key, off);
                    if (o < key) key = o;
                }
                if (lane == 0 && key != U64MAX) atomicMin(&cbf[cc], key);
            }
            __syncthreads();
            bool add = false; float dw = 0.f;
            if (t < NC) {
                u64 k = cbf[t];
                unsigned p = (unsigned)t;
                if (k != U64MAX) {
                    unsigned a = (unsigned)((k >> 7) & 127u), b2 = (unsigned)(k & 127u);
                    unsigned ca = ccomp[a], cbv = ccomp[b2];
                    unsigned c2 = (ca == (unsigned)t) ? cbv : ca;
                    p = c2;
                    if (!(cbf[c2] == k && c2 < (unsigned)t)) {
                        add = true; dw = __uint_as_float((unsigned)(k >> 32));
                    }
                }
                parf[t] = p;
            }
            __syncthreads();
            if (t < NC) {
                unsigned pp = parf[t];
                if (pp != (unsigned)t && parf[pp] == (unsigned)t && (unsigned)t < pp) parf[t] = (unsigned)t;
            }
            __syncthreads();
            if (t < NC) {
                unsigned r2 = parf[t];
                while (parf[r2] != r2) r2 = parf[r2];
                parf[t] = r2;
            }
            __syncthreads();
            if (t < NC) {
                if (add) { unsigned li = atomicAdd(&cnt_s, 1u); deaths[base_s + li] = dw; }
                ccomp[t] = parf[ccomp[t]];
            }
            __syncthreads();
            if (t == 0) base_s += cnt_s;
            __syncthreads();
            if (base_s >= B_N - 1) break;
        }
        __threadfence_block();
        __syncthreads();
    }

    // ---- struct phase ----
    float lo = INFINITY, hi = -INFINITY;
    #pragma unroll
    for (int i = t; i < B_N; i += 1024) {
        lo = fminf(lo, ws[BLO_OFF + i]);
        hi = fmaxf(hi, ws[BHI_OFF + i]);
    }
    #pragma unroll
    for (int off = 32; off; off >>= 1) {
        lo = fminf(lo, __shfl_down(lo, off));
        hi = fmaxf(hi, __shfl_down(hi, off));
    }
    if (lane == 0) { redlo[w] = lo; redhi[w] = hi; }
    __syncthreads();
    lo = redlo[0]; hi = redhi[0];
    #pragma unroll
    for (int k = 1; k < 16; ++k) { lo = fminf(lo, redlo[k]); hi = fmaxf(hi, redhi[k]); }
    float rng = hi - lo;
    float rinv = (rng > 1e-8f) ? 1.0f / rng : 0.0f;

    for (int e = w; e < E_N; e += 16) {
        const float c0 = centres[e * 2], c1 = centres[e * 2 + 1];
        const float s0 = sharp[e * 2],   s1 = sharp[e * 2 + 1];
        const float s1sq = s1 * s1;
        float acc = 0.f;
        for (int p = lane; p < B_N - 1; p += 64) {
            float d = deaths[p] * rinv - c1;
            acc += expf(-s1sq * d * d);
        }
        #pragma unroll
        for (int off = 32; off; off >>= 1) acc += __shfl_down(acc, off);
        if (lane == 0) out[e] = expf(-s0 * s0 * c0 * c0) * acc;
    }
}

extern "C" void kernel_launch(void* const* d_in, const int* in_sizes, int n_in,
                              void* d_out, int out_size, void* d_ws, size_t ws_size,
                              hipStream_t stream) {
    const float* x       = (const float*)d_in[0];
    const float* centres = (const float*)d_in[1];
    const float* sharp   = (const float*)d_in[2];
    float* out = (float*)d_out;
    float* ws  = (float*)d_ws;

    hipLaunchKernelGGL(k_reduce,   dim3(B_N),    dim3(256),  0, stream, x, ws);
    hipLaunchKernelGGL(k_dist,     dim3(64, 64), dim3(256),  0, stream, ws);
    hipLaunchKernelGGL(k_scan0,    dim3(128),    dim3(1024), 0, stream, ws);
    hipLaunchKernelGGL(k_round,    dim3(128),    dim3(1024), 0, stream, ws, 0);
    hipLaunchKernelGGL(k_round,    dim3(128),    dim3(1024), 0, stream, ws, 1);
    hipLaunchKernelGGL(k_round,    dim3(128),    dim3(1024), 0, stream, ws, 0);
    hipLaunchKernelGGL(k_round4c,  dim3(128),    dim3(1024), 0, stream, ws);
    hipLaunchKernelGGL(k_finishstruct, dim3(1),  dim3(1024), 0, stream, ws, centres, sharp, out);
}

// Round 10
// 183.442 us; speedup vs baseline: 1.4942x; 1.0181x over previous
//
#include <hip/hip_runtime.h>
#include <math.h>

// Problem constants
#define B_N 2048
#define T_N 128
#define C_N 3
#define J_N 25
#define E_N 64
#define TC  (T_N*C_N)    // 384 rows per batch
#define TCJ (TC*J_N)     // 9600 floats per batch
#define NQ4 (TCJ/4)      // 2400 float4 per batch
#define NC  128          // contracted size (ncomp <= 128 after 4 unions)

// Workspace layout (float offsets). ~17.1 MiB.
#define D_OFF      0                       // D [2048*2048] f32 (raw-h distances)
#define H_OFF      (B_N*B_N)               // h [2048*25]
#define BLO_OFF    (H_OFF + B_N*J_N)       // per-block lo [2048]
#define BHI_OFF    (BLO_OFF + B_N)         // per-block hi [2048]
#define DEATHS_OFF (BHI_OFF + B_N)         // f32 deaths[2047]
#define BEST_OFF   (DEATHS_OFF + B_N)      // u64 best[2][2048] (even -> 8B aligned)
#define COMP_OFF   (BEST_OFF + 4*B_N)      // u32 comp[2][2048]
#define GC_OFF     (COMP_OFF + 2*B_N)      // u32 gcnt[2]
#define DC_OFF     (GC_OFF + 2)            // u32 Dc[128*128] contracted min-dist (f32 bits)

typedef unsigned long long u64;
#define U64MAX 0xFFFFFFFFFFFFFFFFull
#define U32INF 0xFFFFFFFFu

// One block per batch. Coalesced float4 grid-stride (stride 250 preserves
// j-residue mod 25), register accumulate, tiny LDS reduce. Per-block lo/hi.
__global__ void __launch_bounds__(256) k_reduce(const float* __restrict__ x,
                                                float* __restrict__ ws) {
    __shared__ float4 part[250];
    __shared__ float S[100];
    __shared__ float Mj[25];
    const int t = threadIdx.x, b = blockIdx.x;
    const float4* x4 = (const float4*)(x + (size_t)b * TCJ);
    if (t < 250) {
        float4 a; a.x = a.y = a.z = a.w = 0.f;
        for (int idx = t; idx < NQ4; idx += 250) {
            float4 v = x4[idx];
            a.x += v.x; a.y += v.y; a.z += v.z; a.w += v.w;
        }
        part[t] = a;
    }
    __syncthreads();
    if (t < 25) {
        float4 s = part[t];
        #pragma unroll
        for (int g = 1; g < 10; ++g) {
            float4 v = part[t + 25 * g];
            s.x += v.x; s.y += v.y; s.z += v.z; s.w += v.w;
        }
        S[4*t] = s.x; S[4*t+1] = s.y; S[4*t+2] = s.z; S[4*t+3] = s.w;
    }
    __syncthreads();
    if (t < 25) Mj[t] = (S[t] + S[t+25] + S[t+50] + S[t+75]) * (1.0f / 384.0f);
    __syncthreads();
    if (t < 25) {
        float mj = Mj[t], acc = 0.f;
        #pragma unroll
        for (int i = 0; i < J_N; ++i) { float d = Mj[i] - mj; acc += d * d; }
        float hv = sqrtf(acc);
        ws[H_OFF + b * J_N + t] = hv;
        S[t] = hv;
    }
    __syncthreads();
    if (t == 0) {
        float lo = S[0], hi = S[0];
        #pragma unroll
        for (int i = 1; i < J_N; ++i) { lo = fminf(lo, S[i]); hi = fmaxf(hi, S[i]); }
        ws[BLO_OFF + b] = lo;
        ws[BHI_OFF + b] = hi;
    }
}

// Fused dist + round-0 scan. 128 blocks x 16 rows; wave = one row (ty=t>>6).
// Two 1024-column mega-tiles of h staged in LDS (100 KB); A-row in registers.
// Each wave computes its row's distances, writes D, and keeps the running
// min edge key in-register -> wave shuffle-reduce -> best[0][row]. No second
// pass over D, no separate k_scan0 dispatch. Also seeds comp/gcnt/Dc.
__global__ void __launch_bounds__(1024) k_distscan(float* __restrict__ ws) {
    __shared__ float A[16][26];
    __shared__ float Bsh[1024 * J_N];   // 100 KB
    const int t = threadIdx.x, blk = blockIdx.x;
    const int ty = t >> 6, tx = t & 63;
    const float* h = ws + H_OFF;
    const int row0 = blk * 16;
    for (int idx = t; idx < 16 * J_N; idx += 1024)
        A[idx / J_N][idx % J_N] = h[(row0 + idx / J_N) * J_N + idx % J_N];
    if (blk < 16) ((unsigned*)(ws + DC_OFF))[blk * 1024 + t] = U32INF;
    if (blk == 0) {
        unsigned* gc = (unsigned*)(ws + COMP_OFF);
        gc[t] = (unsigned)t; gc[t + 1024] = (unsigned)(t + 1024);
        if (t == 0) { ((unsigned*)(ws + GC_OFF))[0] = 0u; ((unsigned*)(ws + GC_OFF))[1] = 0u; }
    }
    const int row = row0 + ty;
    float ar[J_N];
    u64 bestk = U64MAX;
    float* D = ws + D_OFF;
    for (int mt = 0; mt < 2; ++mt) {
        __syncthreads();   // protect Bsh (and cover A on mt=0)
        for (int idx = t; idx < 1024 * J_N; idx += 1024)
            Bsh[idx] = h[mt * 1024 * J_N + idx];
        __syncthreads();
        if (mt == 0) {
            #pragma unroll
            for (int k = 0; k < J_N; ++k) ar[k] = A[ty][k];
        }
        #pragma unroll 4
        for (int cc = 0; cc < 16; ++cc) {
            const int col = mt * 1024 + cc * 64 + tx;
            const float* bp = &Bsh[(cc * 64 + tx) * J_N];
            float acc = 0.f;
            #pragma unroll
            for (int k = 0; k < J_N; ++k) { float d = ar[k] - bp[k]; acc += d * d; }
            float dist = sqrtf(fmaxf(acc, 1e-12f));
            D[(size_t)row * B_N + col] = dist;
            if (col != row) {
                unsigned a = min((unsigned)row, (unsigned)col);
                unsigned b2 = max((unsigned)row, (unsigned)col);
                u64 key = ((u64)__float_as_uint(dist) << 32) | (a << 11) | b2;
                if (key < bestk) bestk = key;
            }
        }
    }
    #pragma unroll
    for (int off = 32; off; off >>= 1) {
        u64 o = __shfl_down(bestk, off);
        if (o < bestk) bestk = o;
    }
    if (tx == 0) ((u64*)(ws + BEST_OFF))[row] = bestk;
}

// One Boruvka round: replicated-in-LDS union of best[par_in], then scan with
// the fresh LDS comp -> best[par_in^1]. Reuse pruning: if a row's previous
// best edge is still outgoing, it remains the row min. blk0 persists state.
__global__ void __launch_bounds__(1024) k_round(float* __restrict__ ws, int par_in) {
    unsigned* gcnt = (unsigned*)(ws + GC_OFF);
    const unsigned base = gcnt[par_in];
    if (base >= B_N - 1) return;   // converged: stub
    __shared__ __align__(16) unsigned comp[B_N];  // 8 KB
    __shared__ u64 cb[B_N];                       // 16 KB
    __shared__ unsigned par[B_N];                 // 8 KB
    __shared__ unsigned cnt_s;
    const int t = threadIdx.x, blk = blockIdx.x;
    const unsigned* gcomp_in = (const unsigned*)(ws + COMP_OFF) + par_in * B_N;
    unsigned* gcomp_out = (unsigned*)(ws + COMP_OFF) + (par_in ^ 1) * B_N;
    const u64* bin = (const u64*)(ws + BEST_OFF) + par_in * B_N;
    u64* bout = (u64*)(ws + BEST_OFF) + (par_in ^ 1) * B_N;
    float* deaths = ws + DEATHS_OFF;

    if (t == 0) cnt_s = 0u;
    comp[t] = gcomp_in[t]; comp[t + 1024] = gcomp_in[t + 1024];
    cb[t] = U64MAX; cb[t + 1024] = U64MAX;
    __syncthreads();
    #pragma unroll
    for (int i = t; i < B_N; i += 1024) {
        u64 bk = bin[i];
        if (bk != U64MAX) atomicMin(&cb[comp[i]], bk);
    }
    __syncthreads();
    #pragma unroll
    for (int c = t; c < B_N; c += 1024) {
        u64 k = cb[c];
        unsigned p = (unsigned)c;
        if (k != U64MAX) {
            unsigned a  = (unsigned)((k >> 11) & 0x7FFu);
            unsigned b2 = (unsigned)(k & 0x7FFu);
            unsigned ca = comp[a], cbv = comp[b2];
            unsigned c2 = (ca == (unsigned)c) ? cbv : ca;
            p = c2;
            if (!(cb[c2] == k && c2 < (unsigned)c)) {
                unsigned li = atomicAdd(&cnt_s, 1u);
                if (blk == 0) deaths[base + li] = __uint_as_float((unsigned)(k >> 32));
            }
        }
        par[c] = p;
    }
    __syncthreads();
    #pragma unroll
    for (int c = t; c < B_N; c += 1024) {
        unsigned p = par[c];
        if (p != (unsigned)c && par[p] == (unsigned)c && (unsigned)c < p) par[c] = (unsigned)c;
    }
    __syncthreads();
    #pragma unroll
    for (int c = t; c < B_N; c += 1024) {
        unsigned r = par[c];
        while (true) { unsigned pr = par[r]; if (pr == r) break; r = pr; }
        par[c] = r;
    }
    __syncthreads();
    #pragma unroll
    for (int i = t; i < B_N; i += 1024) comp[i] = par[comp[i]];
    __syncthreads();
    const unsigned newbase = base + cnt_s;
    if (blk == 0) {
        gcomp_out[t] = comp[t]; gcomp_out[t + 1024] = comp[t + 1024];
        if (t == 0) { gcnt[par_in ^ 1] = newbase; if (newbase >= B_N - 1) gcnt[par_in] = newbase; }
    }
    if (newbase >= B_N - 1) return;

    // ---- scan (one wave per row) with reuse pruning ----
    const int w = t >> 6, lane = t & 63;
    const int row = blk * 16 + w;
    const unsigned ci = comp[row];
    u64 prev = bin[row];
    {
        unsigned pa = (unsigned)((prev >> 11) & 0x7FFu);
        unsigned pb = (unsigned)(prev & 0x7FFu);
        unsigned jo = (pa == (unsigned)row) ? pb : pa;
        if (comp[jo] != ci) {          // still outgoing -> still the min
            if (lane == 0) bout[row] = prev;
            return;                    // wave-uniform exit
        }
    }
    const float4* row4 = (const float4*)(ws + D_OFF + (size_t)row * B_N);
    const uint4* comp4 = (const uint4*)comp;
    u64 best = U64MAX;
    #pragma unroll
    for (int k = 0; k < 8; ++k) {
        const int q = k * 64 + lane;
        float4 w4 = row4[q];
        uint4  c4 = comp4[q];
        const unsigned j0 = (unsigned)(q * 4);
        float wv[4] = {w4.x, w4.y, w4.z, w4.w};
        unsigned cv[4] = {c4.x, c4.y, c4.z, c4.w};
        #pragma unroll
        for (int m = 0; m < 4; ++m) {
            if (cv[m] != ci) {
                unsigned j = j0 + m;
                unsigned a = min((unsigned)row, j), b2 = max((unsigned)row, j);
                u64 key = ((u64)__float_as_uint(wv[m]) << 32) | (a << 11) | b2;
                if (key < best) best = key;
            }
        }
    }
    #pragma unroll
    for (int off = 32; off; off >>= 1) {
        u64 o = __shfl_down(best, off);
        if (o < best) best = o;
    }
    if (lane == 0) bout[row] = best;
}

// 4th union (par_in=1) FUSED with contraction to a 128x128 matrix.
// After the replicated union, comp is in LDS in every block; build the
// deterministic rank map (prefix scan of root flags), scan this block's 16
// rows into a 64 KB LDS partial Dc, merge via distinct-address global
// atomicMin. LDS overlay: phase A uses ovl as cb+par, phase B as Dcs.
__global__ void __launch_bounds__(1024) k_round4c(float* __restrict__ ws) {
    unsigned* gcnt = (unsigned*)(ws + GC_OFF);
    const unsigned base = gcnt[1];
    if (base >= B_N - 1) return;   // converged: stub
    __shared__ __align__(16) unsigned comp[B_N];   // 8 KB
    __shared__ __align__(16) unsigned ovl[NC*NC];  // 64 KB overlay
    __shared__ unsigned cflag[B_N];                // 8 KB
    __shared__ unsigned cnt_s, csum[16];
    u64* cb = (u64*)ovl;              // 16 KB (ovl[0..4095])
    unsigned* par = ovl + 4096;       // 8 KB  (ovl[4096..6143])
    const int t = threadIdx.x, blk = blockIdx.x;
    const unsigned* gcomp_in = (const unsigned*)(ws + COMP_OFF) + B_N;  // parity 1
    const u64* bin = (const u64*)(ws + BEST_OFF) + B_N;                 // parity 1
    float* deaths = ws + DEATHS_OFF;

    // ---- phase A: union (identical logic to k_round) ----
    if (t == 0) cnt_s = 0u;
    comp[t] = gcomp_in[t]; comp[t + 1024] = gcomp_in[t + 1024];
    cb[t] = U64MAX; cb[t + 1024] = U64MAX;
    __syncthreads();
    #pragma unroll
    for (int i = t; i < B_N; i += 1024) {
        u64 bk = bin[i];
        if (bk != U64MAX) atomicMin(&cb[comp[i]], bk);
    }
    __syncthreads();
    #pragma unroll
    for (int c = t; c < B_N; c += 1024) {
        u64 k = cb[c];
        unsigned p = (unsigned)c;
        if (k != U64MAX) {
            unsigned a  = (unsigned)((k >> 11) & 0x7FFu);
            unsigned b2 = (unsigned)(k & 0x7FFu);
            unsigned ca = comp[a], cbv = comp[b2];
            unsigned c2 = (ca == (unsigned)c) ? cbv : ca;
            p = c2;
            if (!(cb[c2] == k && c2 < (unsigned)c)) {
                unsigned li = atomicAdd(&cnt_s, 1u);
                if (blk == 0) deaths[base + li] = __uint_as_float((unsigned)(k >> 32));
            }
        }
        par[c] = p;
    }
    __syncthreads();
    #pragma unroll
    for (int c = t; c < B_N; c += 1024) {
        unsigned p = par[c];
        if (p != (unsigned)c && par[p] == (unsigned)c && (unsigned)c < p) par[c] = (unsigned)c;
    }
    __syncthreads();
    #pragma unroll
    for (int c = t; c < B_N; c += 1024) {
        unsigned r = par[c];
        while (true) { unsigned pr = par[r]; if (pr == r) break; r = pr; }
        par[c] = r;
    }
    __syncthreads();
    #pragma unroll
    for (int i = t; i < B_N; i += 1024) comp[i] = par[comp[i]];
    __syncthreads();
    const unsigned newbase = base + cnt_s;
    if (blk == 0 && t == 0) { gcnt[0] = newbase; gcnt[1] = newbase; }
    if (newbase >= B_N - 1) return;   // MST complete: no contraction needed

    // ---- phase B: rank map (deterministic across blocks) ----
    cflag[t] = 0u; cflag[t + 1024] = 0u;
    __syncthreads();
    cflag[comp[t]] = 1u; cflag[comp[t + 1024]] = 1u;
    __syncthreads();
    const unsigned lane = t & 63, w = t >> 6;
    unsigned f0 = cflag[2 * t], f1 = cflag[2 * t + 1];
    unsigned s = f0 + f1, sc = s;
    #pragma unroll
    for (int off = 1; off < 64; off <<= 1) {
        unsigned v = __shfl_up(sc, off);
        if (lane >= (unsigned)off) sc += v;
    }
    if (lane == 63) csum[w] = sc;
    __syncthreads();
    if (t < 16) {
        unsigned v = csum[t], acc = v;
        #pragma unroll
        for (int off = 1; off < 16; off <<= 1) {
            unsigned u2 = __shfl_up(acc, off);
            if (t >= off) acc += u2;
        }
        csum[t] = acc - v;   // exclusive
    }
    __syncthreads();
    unsigned off0 = csum[w] + (sc - s);
    __syncthreads();
    if (f0) cflag[2 * t] = off0;
    if (f1) cflag[2 * t + 1] = off0 + f0;
    __syncthreads();

    // ---- phase C: contract this block's 16 rows into LDS Dcs = ovl ----
    #pragma unroll
    for (int i = 0; i < 16; ++i) ovl[i * 1024 + t] = U32INF;
    __syncthreads();
    {
        const int row = blk * 16 + (int)w;
        const unsigned ci = comp[row];
        const unsigned ri = cflag[ci];
        const float4* row4 = (const float4*)(ws + D_OFF + (size_t)row * B_N);
        const uint4* comp4 = (const uint4*)comp;
        #pragma unroll
        for (int k = 0; k < 8; ++k) {
            const int q = k * 64 + (int)lane;
            float4 w4 = row4[q];
            uint4  c4 = comp4[q];
            float wv[4] = {w4.x, w4.y, w4.z, w4.w};
            unsigned cv[4] = {c4.x, c4.y, c4.z, c4.w};
            #pragma unroll
            for (int m = 0; m < 4; ++m) {
                if (cv[m] != ci) atomicMin(&ovl[ri * NC + cflag[cv[m]]], __float_as_uint(wv[m]));
            }
        }
    }
    __syncthreads();
    unsigned* gDc = (unsigned*)(ws + DC_OFF);
    #pragma unroll
    for (int i = t; i < NC * NC; i += 1024) {
        unsigned v = ovl[i];
        if (v != U32INF) atomicMin(&gDc[i], v);
    }
}

// Finish: in-LDS Boruvka on the 128x128 contracted matrix (<=7 unions,
// t<128 does each union), then the fused structure layer.
__global__ void __launch_bounds__(1024) k_finishstruct(float* __restrict__ ws,
                                                       const float* __restrict__ centres,
                                                       const float* __restrict__ sharp,
                                                       float* __restrict__ out) {
    __shared__ unsigned Dcs[NC * NC];   // 64 KB
    __shared__ u64 cbf[NC];
    __shared__ unsigned parf[NC], ccomp[NC];
    __shared__ unsigned cnt_s, base_s;
    __shared__ float redlo[16], redhi[16];
    const int t = threadIdx.x;
    const int lane = t & 63, w = t >> 6;
    float* deaths = ws + DEATHS_OFF;
    const unsigned base0 = ((const unsigned*)(ws + GC_OFF))[0];

    if (base0 < B_N - 1) {
        const unsigned* gDc = (const unsigned*)(ws + DC_OFF);
        #pragma unroll
        for (int i = 0; i < 16; ++i) Dcs[i * 1024 + t] = gDc[i * 1024 + t];
        if (t < NC) ccomp[t] = (unsigned)t;
        if (t == 0) base_s = base0;
        __syncthreads();
        for (int iter = 0; iter < 7; ++iter) {
            if (t < NC) cbf[t] = U64MAX;
            if (t == 0) cnt_s = 0u;
            __syncthreads();
            // scan: wave w -> rows w*8..w*8+7; lane covers 2 cols
            #pragma unroll
            for (int q = 0; q < 8; ++q) {
                const int r = w * 8 + q;
                const unsigned cc = ccomp[r];
                u64 key = U64MAX;
                #pragma unroll
                for (int hh = 0; hh < 2; ++hh) {
                    const int c = lane + hh * 64;
                    unsigned wv = Dcs[r * NC + c];
                    if (wv != U32INF && ccomp[c] != cc) {
                        unsigned a = min((unsigned)r, (unsigned)c);
                        unsigned b2 = max((unsigned)r, (unsigned)c);
                        u64 k2 = ((u64)wv << 32) | (a << 7) | b2;
                        if (k2 < key) key = k2;
                    }
                }
                #pragma unroll
                for (int off = 32; off; off >>= 1) {
                    u64 o = __shfl_down(key, off);
                    if (o < key) key = o;
                }
                if (lane == 0 && key != U64MAX) atomicMin(&cbf[cc], key);
            }
            __syncthreads();
            bool add = false; float dw = 0.f;
            if (t < NC) {
                u64 k = cbf[t];
                unsigned p = (unsigned)t;
                if (k != U64MAX) {
                    unsigned a = (unsigned)((k >> 7) & 127u), b2 = (unsigned)(k & 127u);
                    unsigned ca = ccomp[a], cbv = ccomp[b2];
                    unsigned c2 = (ca == (unsigned)t) ? cbv : ca;
                    p = c2;
                    if (!(cbf[c2] == k && c2 < (unsigned)t)) {
                        add = true; dw = __uint_as_float((unsigned)(k >> 32));
                    }
                }
                parf[t] = p;
            }
            __syncthreads();
            if (t < NC) {
                unsigned pp = parf[t];
                if (pp != (unsigned)t && parf[pp] == (unsigned)t && (unsigned)t < pp) parf[t] = (unsigned)t;
            }
            __syncthreads();
            if (t < NC) {
                unsigned r2 = parf[t];
                while (parf[r2] != r2) r2 = parf[r2];
                parf[t] = r2;
            }
            __syncthreads();
            if (t < NC) {
                if (add) { unsigned li = atomicAdd(&cnt_s, 1u); deaths[base_s + li] = dw; }
                ccomp[t] = parf[ccomp[t]];
            }
            __syncthreads();
            if (t == 0) base_s += cnt_s;
            __syncthreads();
            if (base_s >= B_N - 1) break;
        }
        __threadfence_block();
        __syncthreads();
    }

    // ---- struct phase ----
    float lo = INFINITY, hi = -INFINITY;
    #pragma unroll
    for (int i = t; i < B_N; i += 1024) {
        lo = fminf(lo, ws[BLO_OFF + i]);
        hi = fmaxf(hi, ws[BHI_OFF + i]);
    }
    #pragma unroll
    for (int off = 32; off; off >>= 1) {
        lo = fminf(lo, __shfl_down(lo, off));
        hi = fmaxf(hi, __shfl_down(hi, off));
    }
    if (lane == 0) { redlo[w] = lo; redhi[w] = hi; }
    __syncthreads();
    lo = redlo[0]; hi = redhi[0];
    #pragma unroll
    for (int k = 1; k < 16; ++k) { lo = fminf(lo, redlo[k]); hi = fmaxf(hi, redhi[k]); }
    float rng = hi - lo;
    float rinv = (rng > 1e-8f) ? 1.0f / rng : 0.0f;

    for (int e = w; e < E_N; e += 16) {
        const float c0 = centres[e * 2], c1 = centres[e * 2 + 1];
        const float s0 = sharp[e * 2],   s1 = sharp[e * 2 + 1];
        const float s1sq = s1 * s1;
        float acc = 0.f;
        for (int p = lane; p < B_N - 1; p += 64) {
            float d = deaths[p] * rinv - c1;
            acc += expf(-s1sq * d * d);
        }
        #pragma unroll
        for (int off = 32; off; off >>= 1) acc += __shfl_down(acc, off);
        if (lane == 0) out[e] = expf(-s0 * s0 * c0 * c0) * acc;
    }
}

extern "C" void kernel_launch(void* const* d_in, const int* in_sizes, int n_in,
                              void* d_out, int out_size, void* d_ws, size_t ws_size,
                              hipStream_t stream) {
    const float* x       = (const float*)d_in[0];
    const float* centres = (const float*)d_in[1];
    const float* sharp   = (const float*)d_in[2];
    float* out = (float*)d_out;
    float* ws  = (float*)d_ws;

    hipLaunchKernelGGL(k_reduce,   dim3(B_N),  dim3(256),  0, stream, x, ws);
    hipLaunchKernelGGL(k_distscan, dim3(128),  dim3(1024), 0, stream, ws);
    hipLaunchKernelGGL(k_round,    dim3(128),  dim3(1024), 0, stream, ws, 0);
    hipLaunchKernelGGL(k_round,    dim3(128),  dim3(1024), 0, stream, ws, 1);
    hipLaunchKernelGGL(k_round,    dim3(128),  dim3(1024), 0, stream, ws, 0);
    hipLaunchKernelGGL(k_round4c,  dim3(128),  dim3(1024), 0, stream, ws);
    hipLaunchKernelGGL(k_finishstruct, dim3(1), dim3(1024), 0, stream, ws, centres, sharp, out);
}

// Round 11
// 178.813 us; speedup vs baseline: 1.5329x; 1.0259x over previous
//
#include <hip/hip_runtime.h>
#include <math.h>

// Problem constants
#define B_N 2048
#define T_N 128
#define C_N 3
#define J_N 25
#define E_N 64
#define TC  (T_N*C_N)    // 384 rows per batch
#define TCJ (TC*J_N)     // 9600 floats per batch
#define NQ4 (TCJ/4)      // 2400 float4 per batch
#define NC  256          // contracted size (ncomp <= 256 after 3 unions)

// Workspace layout (float offsets). ~17.4 MiB.
#define D_OFF      0                       // D [2048*2048] f32 (raw-h distances)
#define H_OFF      (B_N*B_N)               // h [2048*25]
#define BLO_OFF    (H_OFF + B_N*J_N)       // per-block lo [2048]
#define BHI_OFF    (BLO_OFF + B_N)         // per-block hi [2048]
#define DEATHS_OFF (BHI_OFF + B_N)         // f32 deaths[2047]
#define BEST_OFF   (DEATHS_OFF + B_N)      // u64 best[2][2048] (even -> 8B aligned)
#define COMP_OFF   (BEST_OFF + 4*B_N)      // u32 comp[2][2048]
#define GC_OFF     (COMP_OFF + 2*B_N)      // u32 gcnt[2]
#define DC_OFF     (GC_OFF + 2)            // u32 Dc[256*256] contracted min-dist (f32 bits)

typedef unsigned long long u64;
#define U64MAX 0xFFFFFFFFFFFFFFFFull
#define U32INF 0xFFFFFFFFu

// One block per batch. Coalesced float4 grid-stride (stride 250 preserves
// j-residue mod 25), register accumulate, tiny LDS reduce. Per-block lo/hi.
__global__ void __launch_bounds__(256) k_reduce(const float* __restrict__ x,
                                                float* __restrict__ ws) {
    __shared__ float4 part[250];
    __shared__ float S[100];
    __shared__ float Mj[25];
    const int t = threadIdx.x, b = blockIdx.x;
    const float4* x4 = (const float4*)(x + (size_t)b * TCJ);
    if (t < 250) {
        float4 a; a.x = a.y = a.z = a.w = 0.f;
        for (int idx = t; idx < NQ4; idx += 250) {
            float4 v = x4[idx];
            a.x += v.x; a.y += v.y; a.z += v.z; a.w += v.w;
        }
        part[t] = a;
    }
    __syncthreads();
    if (t < 25) {
        float4 s = part[t];
        #pragma unroll
        for (int g = 1; g < 10; ++g) {
            float4 v = part[t + 25 * g];
            s.x += v.x; s.y += v.y; s.z += v.z; s.w += v.w;
        }
        S[4*t] = s.x; S[4*t+1] = s.y; S[4*t+2] = s.z; S[4*t+3] = s.w;
    }
    __syncthreads();
    if (t < 25) Mj[t] = (S[t] + S[t+25] + S[t+50] + S[t+75]) * (1.0f / 384.0f);
    __syncthreads();
    if (t < 25) {
        float mj = Mj[t], acc = 0.f;
        #pragma unroll
        for (int i = 0; i < J_N; ++i) { float d = Mj[i] - mj; acc += d * d; }
        float hv = sqrtf(acc);
        ws[H_OFF + b * J_N + t] = hv;
        S[t] = hv;
    }
    __syncthreads();
    if (t == 0) {
        float lo = S[0], hi = S[0];
        #pragma unroll
        for (int i = 1; i < J_N; ++i) { lo = fminf(lo, S[i]); hi = fmaxf(hi, S[i]); }
        ws[BLO_OFF + b] = lo;
        ws[BHI_OFF + b] = hi;
    }
}

// Fused dist + round-0 scan. 128 blocks x 16 rows; wave = one row.
// Two 1024-column mega-tiles of h staged in LDS; A-row in registers. Each
// wave computes its row's distances, writes D, keeps the running min edge
// key in-register -> shuffle-reduce -> best[0][row]. Seeds comp/gcnt/Dc.
__global__ void __launch_bounds__(1024) k_distscan(float* __restrict__ ws) {
    __shared__ float A[16][26];
    __shared__ float Bsh[1024 * J_N];   // 100 KB
    const int t = threadIdx.x, blk = blockIdx.x;
    const int ty = t >> 6, tx = t & 63;
    const float* h = ws + H_OFF;
    const int row0 = blk * 16;
    for (int idx = t; idx < 16 * J_N; idx += 1024)
        A[idx / J_N][idx % J_N] = h[(row0 + idx / J_N) * J_N + idx % J_N];
    if (blk < 64) ((unsigned*)(ws + DC_OFF))[blk * 1024 + t] = U32INF;
    if (blk == 0) {
        unsigned* gc = (unsigned*)(ws + COMP_OFF);
        gc[t] = (unsigned)t; gc[t + 1024] = (unsigned)(t + 1024);
        if (t == 0) { ((unsigned*)(ws + GC_OFF))[0] = 0u; ((unsigned*)(ws + GC_OFF))[1] = 0u; }
    }
    const int row = row0 + ty;
    float ar[J_N];
    u64 bestk = U64MAX;
    float* D = ws + D_OFF;
    for (int mt = 0; mt < 2; ++mt) {
        __syncthreads();   // protect Bsh (and cover A on mt=0)
        for (int idx = t; idx < 1024 * J_N; idx += 1024)
            Bsh[idx] = h[mt * 1024 * J_N + idx];
        __syncthreads();
        if (mt == 0) {
            #pragma unroll
            for (int k = 0; k < J_N; ++k) ar[k] = A[ty][k];
        }
        #pragma unroll 4
        for (int cc = 0; cc < 16; ++cc) {
            const int col = mt * 1024 + cc * 64 + tx;
            const float* bp = &Bsh[(cc * 64 + tx) * J_N];
            float acc = 0.f;
            #pragma unroll
            for (int k = 0; k < J_N; ++k) { float d = ar[k] - bp[k]; acc += d * d; }
            float dist = sqrtf(fmaxf(acc, 1e-12f));
            D[(size_t)row * B_N + col] = dist;
            if (col != row) {
                unsigned a = min((unsigned)row, (unsigned)col);
                unsigned b2 = max((unsigned)row, (unsigned)col);
                u64 key = ((u64)__float_as_uint(dist) << 32) | (a << 11) | b2;
                if (key < bestk) bestk = key;
            }
        }
    }
    #pragma unroll
    for (int off = 32; off; off >>= 1) {
        u64 o = __shfl_down(bestk, off);
        if (o < bestk) bestk = o;
    }
    if (tx == 0) ((u64*)(ws + BEST_OFF))[row] = bestk;
}

// One Boruvka round: replicated-in-LDS union of best[par_in], then scan with
// the fresh LDS comp -> best[par_in^1]. Reuse pruning: if a row's previous
// best edge is still outgoing, it remains the row min. blk0 persists state.
__global__ void __launch_bounds__(1024) k_round(float* __restrict__ ws, int par_in) {
    unsigned* gcnt = (unsigned*)(ws + GC_OFF);
    const unsigned base = gcnt[par_in];
    if (base >= B_N - 1) return;   // converged: stub
    __shared__ __align__(16) unsigned comp[B_N];  // 8 KB
    __shared__ u64 cb[B_N];                       // 16 KB
    __shared__ unsigned par[B_N];                 // 8 KB
    __shared__ unsigned cnt_s;
    const int t = threadIdx.x, blk = blockIdx.x;
    const unsigned* gcomp_in = (const unsigned*)(ws + COMP_OFF) + par_in * B_N;
    unsigned* gcomp_out = (unsigned*)(ws + COMP_OFF) + (par_in ^ 1) * B_N;
    const u64* bin = (const u64*)(ws + BEST_OFF) + par_in * B_N;
    u64* bout = (u64*)(ws + BEST_OFF) + (par_in ^ 1) * B_N;
    float* deaths = ws + DEATHS_OFF;

    if (t == 0) cnt_s = 0u;
    comp[t] = gcomp_in[t]; comp[t + 1024] = gcomp_in[t + 1024];
    cb[t] = U64MAX; cb[t + 1024] = U64MAX;
    __syncthreads();
    #pragma unroll
    for (int i = t; i < B_N; i += 1024) {
        u64 bk = bin[i];
        if (bk != U64MAX) atomicMin(&cb[comp[i]], bk);
    }
    __syncthreads();
    #pragma unroll
    for (int c = t; c < B_N; c += 1024) {
        u64 k = cb[c];
        unsigned p = (unsigned)c;
        if (k != U64MAX) {
            unsigned a  = (unsigned)((k >> 11) & 0x7FFu);
            unsigned b2 = (unsigned)(k & 0x7FFu);
            unsigned ca = comp[a], cbv = comp[b2];
            unsigned c2 = (ca == (unsigned)c) ? cbv : ca;
            p = c2;
            if (!(cb[c2] == k && c2 < (unsigned)c)) {
                unsigned li = atomicAdd(&cnt_s, 1u);
                if (blk == 0) deaths[base + li] = __uint_as_float((unsigned)(k >> 32));
            }
        }
        par[c] = p;
    }
    __syncthreads();
    #pragma unroll
    for (int c = t; c < B_N; c += 1024) {
        unsigned p = par[c];
        if (p != (unsigned)c && par[p] == (unsigned)c && (unsigned)c < p) par[c] = (unsigned)c;
    }
    __syncthreads();
    #pragma unroll
    for (int c = t; c < B_N; c += 1024) {
        unsigned r = par[c];
        while (true) { unsigned pr = par[r]; if (pr == r) break; r = pr; }
        par[c] = r;
    }
    __syncthreads();
    #pragma unroll
    for (int i = t; i < B_N; i += 1024) comp[i] = par[comp[i]];
    __syncthreads();
    const unsigned newbase = base + cnt_s;
    if (blk == 0) {
        gcomp_out[t] = comp[t]; gcomp_out[t + 1024] = comp[t + 1024];
        if (t == 0) { gcnt[par_in ^ 1] = newbase; if (newbase >= B_N - 1) gcnt[par_in] = newbase; }
    }
    if (newbase >= B_N - 1) return;

    // ---- scan (one wave per row) with reuse pruning ----
    const int w = t >> 6, lane = t & 63;
    const int row = blk * 16 + w;
    const unsigned ci = comp[row];
    u64 prev = bin[row];
    {
        unsigned pa = (unsigned)((prev >> 11) & 0x7FFu);
        unsigned pb = (unsigned)(prev & 0x7FFu);
        unsigned jo = (pa == (unsigned)row) ? pb : pa;
        if (comp[jo] != ci) {          // still outgoing -> still the min
            if (lane == 0) bout[row] = prev;
            return;                    // wave-uniform exit
        }
    }
    const float4* row4 = (const float4*)(ws + D_OFF + (size_t)row * B_N);
    const uint4* comp4 = (const uint4*)comp;
    u64 best = U64MAX;
    #pragma unroll
    for (int k = 0; k < 8; ++k) {
        const int q = k * 64 + lane;
        float4 w4 = row4[q];
        uint4  c4 = comp4[q];
        const unsigned j0 = (unsigned)(q * 4);
        float wv[4] = {w4.x, w4.y, w4.z, w4.w};
        unsigned cv[4] = {c4.x, c4.y, c4.z, c4.w};
        #pragma unroll
        for (int m = 0; m < 4; ++m) {
            if (cv[m] != ci) {
                unsigned j = j0 + m;
                unsigned a = min((unsigned)row, j), b2 = max((unsigned)row, j);
                u64 key = ((u64)__float_as_uint(wv[m]) << 32) | (a << 11) | b2;
                if (key < best) best = key;
            }
        }
    }
    #pragma unroll
    for (int off = 32; off; off >>= 1) {
        u64 o = __shfl_down(best, off);
        if (o < best) best = o;
    }
    if (lane == 0) bout[row] = best;
}

// 3rd union (par_in=0) FUSED with contraction to a 256x256 matrix.
// After the replicated union (ncomp <= 256 guaranteed), build the
// deterministic rank map (prefix scan of root flags), scan this block's 16
// rows into a per-row-local LDS partial pd[16][256] (16 KB), merge via
// distinct-address global atomicMin into Dc[256*256].
__global__ void __launch_bounds__(1024) k_round3c(float* __restrict__ ws) {
    unsigned* gcnt = (unsigned*)(ws + GC_OFF);
    const unsigned base = gcnt[0];
    if (base >= B_N - 1) return;   // can't happen before round 4; guard anyway
    __shared__ __align__(16) unsigned comp[B_N];   // 8 KB
    __shared__ u64 cb[B_N];                        // 16 KB
    __shared__ unsigned par[B_N];                  // 8 KB
    __shared__ unsigned cflag[B_N];                // 8 KB
    __shared__ unsigned pd[16][NC];                // 16 KB partial contracted rows
    __shared__ unsigned cnt_s, csum[16];
    const int t = threadIdx.x, blk = blockIdx.x;
    const unsigned* gcomp_in = (const unsigned*)(ws + COMP_OFF);  // parity 0
    const u64* bin = (const u64*)(ws + BEST_OFF);                 // parity 0
    float* deaths = ws + DEATHS_OFF;

    // ---- phase A: union (identical logic to k_round) ----
    if (t == 0) cnt_s = 0u;
    comp[t] = gcomp_in[t]; comp[t + 1024] = gcomp_in[t + 1024];
    cb[t] = U64MAX; cb[t + 1024] = U64MAX;
    __syncthreads();
    #pragma unroll
    for (int i = t; i < B_N; i += 1024) {
        u64 bk = bin[i];
        if (bk != U64MAX) atomicMin(&cb[comp[i]], bk);
    }
    __syncthreads();
    #pragma unroll
    for (int c = t; c < B_N; c += 1024) {
        u64 k = cb[c];
        unsigned p = (unsigned)c;
        if (k != U64MAX) {
            unsigned a  = (unsigned)((k >> 11) & 0x7FFu);
            unsigned b2 = (unsigned)(k & 0x7FFu);
            unsigned ca = comp[a], cbv = comp[b2];
            unsigned c2 = (ca == (unsigned)c) ? cbv : ca;
            p = c2;
            if (!(cb[c2] == k && c2 < (unsigned)c)) {
                unsigned li = atomicAdd(&cnt_s, 1u);
                if (blk == 0) deaths[base + li] = __uint_as_float((unsigned)(k >> 32));
            }
        }
        par[c] = p;
    }
    __syncthreads();
    #pragma unroll
    for (int c = t; c < B_N; c += 1024) {
        unsigned p = par[c];
        if (p != (unsigned)c && par[p] == (unsigned)c && (unsigned)c < p) par[c] = (unsigned)c;
    }
    __syncthreads();
    #pragma unroll
    for (int c = t; c < B_N; c += 1024) {
        unsigned r = par[c];
        while (true) { unsigned pr = par[r]; if (pr == r) break; r = pr; }
        par[c] = r;
    }
    __syncthreads();
    #pragma unroll
    for (int i = t; i < B_N; i += 1024) comp[i] = par[comp[i]];
    __syncthreads();
    const unsigned newbase = base + cnt_s;
    if (blk == 0 && t == 0) { gcnt[0] = newbase; gcnt[1] = newbase; }
    if (newbase >= B_N - 1) return;

    // ---- phase B: rank map (deterministic across blocks) ----
    cflag[t] = 0u; cflag[t + 1024] = 0u;
    __syncthreads();
    cflag[comp[t]] = 1u; cflag[comp[t + 1024]] = 1u;
    __syncthreads();
    const unsigned lane = t & 63, w = t >> 6;
    unsigned f0 = cflag[2 * t], f1 = cflag[2 * t + 1];
    unsigned s = f0 + f1, sc = s;
    #pragma unroll
    for (int off = 1; off < 64; off <<= 1) {
        unsigned v = __shfl_up(sc, off);
        if (lane >= (unsigned)off) sc += v;
    }
    if (lane == 63) csum[w] = sc;
    __syncthreads();
    if (t < 16) {
        unsigned v = csum[t], acc = v;
        #pragma unroll
        for (int off = 1; off < 16; off <<= 1) {
            unsigned u2 = __shfl_up(acc, off);
            if (t >= off) acc += u2;
        }
        csum[t] = acc - v;   // exclusive
    }
    __syncthreads();
    unsigned off0 = csum[w] + (sc - s);
    __syncthreads();
    if (f0) cflag[2 * t] = off0;
    if (f1) cflag[2 * t + 1] = off0 + f0;
    __syncthreads();

    // ---- phase C: contract this block's 16 rows into pd[16][256] ----
    #pragma unroll
    for (int i = 0; i < 4; ++i) pd[0][i * 1024 + t] = U32INF;
    __syncthreads();
    const int row = blk * 16 + (int)w;
    const unsigned ci = comp[row];
    {
        const float4* row4 = (const float4*)(ws + D_OFF + (size_t)row * B_N);
        const uint4* comp4 = (const uint4*)comp;
        #pragma unroll
        for (int k = 0; k < 8; ++k) {
            const int q = k * 64 + (int)lane;
            float4 w4 = row4[q];
            uint4  c4 = comp4[q];
            float wv[4] = {w4.x, w4.y, w4.z, w4.w};
            unsigned cv[4] = {c4.x, c4.y, c4.z, c4.w};
            #pragma unroll
            for (int m = 0; m < 4; ++m) {
                if (cv[m] != ci) atomicMin(&pd[w][cflag[cv[m]]], __float_as_uint(wv[m]));
            }
        }
    }
    __syncthreads();
    unsigned* gDc = (unsigned*)(ws + DC_OFF);
    const unsigned ri = cflag[ci];
    for (int j2 = (int)lane; j2 < NC; j2 += 64) {
        unsigned v = pd[w][j2];
        if (v != U32INF) atomicMin(&gDc[ri * NC + j2], v);
    }
}

// Finish: in-LDS Boruvka on the 256x256 contracted matrix with bf16-quantized
// weights (128 KB LDS; top-16 f32 bits, monotone truncation -> <=0.4% rel
// error on <=255 contracted deaths only), then the fused structure layer.
__global__ void __launch_bounds__(1024) k_finishstruct(float* __restrict__ ws,
                                                       const float* __restrict__ centres,
                                                       const float* __restrict__ sharp,
                                                       float* __restrict__ out) {
    __shared__ unsigned short Dcs[NC * NC];   // 128 KB
    __shared__ u64 cbf[NC];
    __shared__ unsigned parf[NC], ccomp[NC];
    __shared__ unsigned cnt_s, base_s;
    __shared__ float redlo[16], redhi[16];
    const int t = threadIdx.x;
    const int lane = t & 63, w = t >> 6;
    float* deaths = ws + DEATHS_OFF;
    const unsigned base0 = ((const unsigned*)(ws + GC_OFF))[0];

    if (base0 < B_N - 1) {
        const unsigned* gDc = (const unsigned*)(ws + DC_OFF);
        #pragma unroll
        for (int i = 0; i < 64; ++i) {
            unsigned v = gDc[i * 1024 + t];
            Dcs[i * 1024 + t] = (unsigned short)(v >> 16);   // U32INF -> 0xFFFF
        }
        if (t < NC) ccomp[t] = (unsigned)t;
        if (t == 0) base_s = base0;
        __syncthreads();
        for (int iter = 0; iter < 8; ++iter) {
            if (t < NC) cbf[t] = U64MAX;
            if (t == 0) cnt_s = 0u;
            __syncthreads();
            // scan: wave w -> 16 rows; lane covers 4 cols
            #pragma unroll
            for (int q = 0; q < 16; ++q) {
                const int r = w * 16 + q;
                const unsigned cc = ccomp[r];
                u64 key = U64MAX;
                #pragma unroll
                for (int hh = 0; hh < 4; ++hh) {
                    const int c = lane + hh * 64;
                    unsigned wv = Dcs[r * NC + c];
                    if (wv != 0xFFFFu && ccomp[c] != cc) {
                        unsigned a = min((unsigned)r, (unsigned)c);
                        unsigned b2 = max((unsigned)r, (unsigned)c);
                        u64 k2 = ((u64)wv << 32) | (a << 8) | b2;
                        if (k2 < key) key = k2;
                    }
                }
                #pragma unroll
                for (int off = 32; off; off >>= 1) {
                    u64 o = __shfl_down(key, off);
                    if (o < key) key = o;
                }
                if (lane == 0 && key != U64MAX) atomicMin(&cbf[cc], key);
            }
            __syncthreads();
            bool add = false; float dw = 0.f;
            if (t < NC) {
                u64 k = cbf[t];
                unsigned p = (unsigned)t;
                if (k != U64MAX) {
                    unsigned a = (unsigned)((k >> 8) & 255u), b2 = (unsigned)(k & 255u);
                    unsigned ca = ccomp[a], cbv = ccomp[b2];
                    unsigned c2 = (ca == (unsigned)t) ? cbv : ca;
                    p = c2;
                    if (!(cbf[c2] == k && c2 < (unsigned)t)) {
                        add = true;
                        dw = __uint_as_float((unsigned)(k >> 32) << 16);
                    }
                }
                parf[t] = p;
            }
            __syncthreads();
            if (t < NC) {
                unsigned pp = parf[t];
                if (pp != (unsigned)t && parf[pp] == (unsigned)t && (unsigned)t < pp) parf[t] = (unsigned)t;
            }
            __syncthreads();
            if (t < NC) {
                unsigned r2 = parf[t];
                while (parf[r2] != r2) r2 = parf[r2];
                parf[t] = r2;
            }
            __syncthreads();
            if (t < NC) {
                if (add) { unsigned li = atomicAdd(&cnt_s, 1u); deaths[base_s + li] = dw; }
                ccomp[t] = parf[ccomp[t]];
            }
            __syncthreads();
            if (t == 0) base_s += cnt_s;
            __syncthreads();
            if (base_s >= B_N - 1) break;
        }
        __syncthreads();
    }

    // ---- struct phase ----
    float lo = INFINITY, hi = -INFINITY;
    #pragma unroll
    for (int i = t; i < B_N; i += 1024) {
        lo = fminf(lo, ws[BLO_OFF + i]);
        hi = fmaxf(hi, ws[BHI_OFF + i]);
    }
    #pragma unroll
    for (int off = 32; off; off >>= 1) {
        lo = fminf(lo, __shfl_down(lo, off));
        hi = fmaxf(hi, __shfl_down(hi, off));
    }
    if (lane == 0) { redlo[w] = lo; redhi[w] = hi; }
    __syncthreads();
    lo = redlo[0]; hi = redhi[0];
    #pragma unroll
    for (int k = 1; k < 16; ++k) { lo = fminf(lo, redlo[k]); hi = fmaxf(hi, redhi[k]); }
    float rng = hi - lo;
    float rinv = (rng > 1e-8f) ? 1.0f / rng : 0.0f;

    for (int e = w; e < E_N; e += 16) {
        const float c0 = centres[e * 2], c1 = centres[e * 2 + 1];
        const float s0 = sharp[e * 2],   s1 = sharp[e * 2 + 1];
        const float s1sq = s1 * s1;
        float acc = 0.f;
        for (int p = lane; p < B_N - 1; p += 64) {
            float d = deaths[p] * rinv - c1;
            acc += expf(-s1sq * d * d);
        }
        #pragma unroll
        for (int off = 32; off; off >>= 1) acc += __shfl_down(acc, off);
        if (lane == 0) out[e] = expf(-s0 * s0 * c0 * c0) * acc;
    }
}

extern "C" void kernel_launch(void* const* d_in, const int* in_sizes, int n_in,
                              void* d_out, int out_size, void* d_ws, size_t ws_size,
                              hipStream_t stream) {
    const float* x       = (const float*)d_in[0];
    const float* centres = (const float*)d_in[1];
    const float* sharp   = (const float*)d_in[2];
    float* out = (float*)d_out;
    float* ws  = (float*)d_ws;

    hipLaunchKernelGGL(k_reduce,   dim3(B_N),  dim3(256),  0, stream, x, ws);
    hipLaunchKernelGGL(k_distscan, dim3(128),  dim3(1024), 0, stream, ws);
    hipLaunchKernelGGL(k_round,    dim3(128),  dim3(1024), 0, stream, ws, 0);
    hipLaunchKernelGGL(k_round,    dim3(128),  dim3(1024), 0, stream, ws, 1);
    hipLaunchKernelGGL(k_round3c,  dim3(128),  dim3(1024), 0, stream, ws);
    hipLaunchKernelGGL(k_finishstruct, dim3(1), dim3(1024), 0, stream, ws, centres, sharp, out);
}